// Round 6
// baseline (182.703 us; speedup 1.0000x reference)
//
#include <hip/hip_runtime.h>
#include <hip/hip_cooperative_groups.h>
#include <math.h>

namespace cg = cooperative_groups;

// EnGMPHD update kernel for MI355X (round 6 = round 5 + compile fix).
// Single cooperative mega-kernel:
//   Phase A: blocks < NB_STATS compute stat partials (stat-major, no atomics)
//   grid.sync()
//   Phase C: particle blocks reduce partials -> P in LDS, per-particle
//            H/S/Chol/Sinv/K (f32 transcendentals, f64 algebra) -> stage+pack
//   grid.sync()
//   Phase D: task loop, replicate tasks first (read stage once, nt-store to
//            all M slices), then update tasks (8 m's per task, LDS repack ->
//            contiguous nt float4 stores).
// Fallback (no coop / small ws): round-4 3-kernel path.

#define NDIM 6
#define MDIM 3
#define NB_STATS 128
#define GROUP_M 8
typedef float f32x4 __attribute__((ext_vector_type(4)));

__device__ __forceinline__ bool mask_true(const int* m32, const unsigned char* m8, int m) {
    return (m32[m] != 0) || (m8[m] != 0);
}

// ---------- shared device bodies ----------

__device__ __forceinline__ void stats_body(const float* __restrict__ means, int N,
                                           double* __restrict__ partials, int nblocks) {
    double sx[6];
    double sxx[21];
#pragma unroll
    for (int i = 0; i < 6; ++i) sx[i] = 0.0;
#pragma unroll
    for (int i = 0; i < 21; ++i) sxx[i] = 0.0;

    int stride = nblocks * 256;
    for (int n = blockIdx.x * 256 + threadIdx.x; n < N; n += stride) {
        const float2* mp = (const float2*)(means + (size_t)n * 6);
        float2 a = mp[0], b = mp[1], c = mp[2];
        double x[6] = {a.x, a.y, b.x, b.y, c.x, c.y};
        int p = 0;
#pragma unroll
        for (int i = 0; i < 6; ++i) {
            sx[i] += x[i];
#pragma unroll
            for (int j = i; j < 6; ++j) sxx[p++] += x[i] * x[j];
        }
    }
#pragma unroll
    for (int off = 32; off >= 1; off >>= 1) {
#pragma unroll
        for (int i = 0; i < 6; ++i) sx[i] += __shfl_down(sx[i], off);
#pragma unroll
        for (int i = 0; i < 21; ++i) sxx[i] += __shfl_down(sxx[i], off);
    }
    __shared__ double lds[4][27];
    int wave = threadIdx.x >> 6;
    if ((threadIdx.x & 63) == 0) {
#pragma unroll
        for (int i = 0; i < 6; ++i) lds[wave][i] = sx[i];
#pragma unroll
        for (int i = 0; i < 21; ++i) lds[wave][6 + i] = sxx[i];
    }
    __syncthreads();
    if (threadIdx.x < 27) {
        double v = lds[0][threadIdx.x] + lds[1][threadIdx.x] +
                   lds[2][threadIdx.x] + lds[3][threadIdx.x];
        partials[threadIdx.x * NB_STATS + blockIdx.x] = v;
    }
    __syncthreads();
}

// Reduce partials (threads 0..26) + build P (thread 0) into sP/sPf. Caller syncs.
__device__ __forceinline__ void build_P_block(const double* __restrict__ partials, int N,
                                              double* __restrict__ sStats,
                                              double* __restrict__ sP,
                                              float* __restrict__ sPf) {
    if (threadIdx.x < 27) {
        const double* src = partials + (size_t)threadIdx.x * NB_STATS;
        double acc = 0.0;
#pragma unroll 8
        for (int b = 0; b < NB_STATS; ++b) acc += src[b];
        sStats[threadIdx.x] = acc;
    }
    __syncthreads();
    if (threadIdx.x == 0) {
        double mean[6];
#pragma unroll
        for (int i = 0; i < 6; ++i) mean[i] = sStats[i] / (double)N;
        double bandwidth = pow(4.0 / ((double)N * 8.0), 0.2);  // d=6
        int p = 0;
        for (int i = 0; i < 6; ++i) {
            for (int j = i; j < 6; ++j) {
                double emp = (sStats[6 + p] - (double)N * mean[i] * mean[j]) / (double)(N - 1);
                double dd = (double)(j - i);
                double val = bandwidth * emp * exp(-(dd * dd) / 18.0);  // L = 3.0
                sP[i * 6 + j] = val;
                sP[j * 6 + i] = val;
                ++p;
            }
        }
    }
    __syncthreads();
    if (threadIdx.x < 36) sPf[threadIdx.x] = (float)sP[threadIdx.x];
    __syncthreads();
}

__device__ __forceinline__ void particle_body(const float* __restrict__ means,
                                              const float* __restrict__ Rin,
                                              const double* __restrict__ sP,
                                              const float* __restrict__ sPf,
                                              float* __restrict__ stage,
                                              float* __restrict__ pack, int n) {
    const float2* mp = (const float2*)(means + (size_t)n * 6);
    float2 ma = mp[0], mb = mp[1];
    float px = ma.x, py = ma.y, pz = mb.x;
    float s2 = px * px + py * py;
    float r2 = s2 + pz * pz;
    float rho = sqrtf(r2);
    float s = sqrtf(s2);
    float hx0 = rho;
    float hx1 = atan2f(py, px);
    float hx2 = asinf(pz / rho);
    float H[3][3];
    H[0][0] = px / rho; H[0][1] = py / rho; H[0][2] = pz / rho;
    H[1][0] = -py / s2; H[1][1] = px / s2;  H[1][2] = 0.0f;
    float invr2s = 1.0f / (r2 * s);
    H[2][0] = -pz * px * invr2s; H[2][1] = -pz * py * invr2s; H[2][2] = s / r2;

    double T[3][3];
#pragma unroll
    for (int i = 0; i < 3; ++i)
#pragma unroll
        for (int k = 0; k < 3; ++k)
            T[i][k] = (double)H[i][0] * sP[0 * 6 + k] + (double)H[i][1] * sP[1 * 6 + k] +
                      (double)H[i][2] * sP[2 * 6 + k];
    double S[3][3];
#pragma unroll
    for (int i = 0; i < 3; ++i)
#pragma unroll
        for (int l = 0; l < 3; ++l)
            S[i][l] = T[i][0] * (double)H[l][0] + T[i][1] * (double)H[l][1] +
                      T[i][2] * (double)H[l][2] + (double)Rin[i * 3 + l];

    double L00 = sqrt(S[0][0]);
    double L10 = S[1][0] / L00;
    double L20 = S[2][0] / L00;
    double L11 = sqrt(S[1][1] - L10 * L10);
    double L21 = (S[2][1] - L20 * L10) / L11;
    double L22 = sqrt(S[2][2] - L20 * L20 - L21 * L21);
    float logdet = logf((float)(L00 * L11 * L22));

    double a00 = S[0][0], a01 = S[0][1], a02 = S[0][2];
    double a11 = S[1][1], a12 = S[1][2], a22 = S[2][2];
    double c00 = a11 * a22 - a12 * a12;
    double c01 = a02 * a12 - a01 * a22;
    double c02 = a01 * a12 - a02 * a11;
    double c11 = a00 * a22 - a02 * a02;
    double c12 = a01 * a02 - a00 * a12;
    double c22 = a00 * a11 - a01 * a01;
    double invdet = 1.0 / (a00 * c00 + a01 * c01 + a02 * c02);
    double Si[3][3] = {{c00 * invdet, c01 * invdet, c02 * invdet},
                       {c01 * invdet, c11 * invdet, c12 * invdet},
                       {c02 * invdet, c12 * invdet, c22 * invdet}};

    float Kf[6][3];
#pragma unroll
    for (int i = 0; i < 6; ++i) {
        double pht[3];
#pragma unroll
        for (int k = 0; k < 3; ++k)
            pht[k] = sP[i * 6 + 0] * (double)H[k][0] + sP[i * 6 + 1] * (double)H[k][1] +
                     sP[i * 6 + 2] * (double)H[k][2];
#pragma unroll
        for (int l = 0; l < 3; ++l)
            Kf[i][l] = (float)(pht[0] * Si[0][l] + pht[1] * Si[1][l] + pht[2] * Si[2][l]);
    }

    float KH[6][3];
#pragma unroll
    for (int i = 0; i < 6; ++i)
#pragma unroll
        for (int j = 0; j < 3; ++j)
            KH[i][j] = Kf[i][0] * H[0][j] + Kf[i][1] * H[1][j] + Kf[i][2] * H[2][j];
    float cp[36];
#pragma unroll
    for (int i = 0; i < 6; ++i)
#pragma unroll
        for (int j = 0; j < 6; ++j)
            cp[i * 6 + j] = sPf[i * 6 + j] - (KH[i][0] * sPf[0 * 6 + j] +
                                              KH[i][1] * sPf[1 * 6 + j] +
                                              KH[i][2] * sPf[2 * 6 + j]);
    f32x4* dst = (f32x4*)(stage + (size_t)n * 36);
#pragma unroll
    for (int q = 0; q < 9; ++q) {
        f32x4 v = {cp[q * 4 + 0], cp[q * 4 + 1], cp[q * 4 + 2], cp[q * 4 + 3]};
        dst[q] = v;
    }

    float pk[28];
    pk[0] = hx0; pk[1] = hx1; pk[2] = hx2; pk[3] = logdet;
    pk[4] = (float)L00; pk[5] = (float)L10; pk[6] = (float)L11;
    pk[7] = (float)L20; pk[8] = (float)L21; pk[9] = (float)L22;
#pragma unroll
    for (int i = 0; i < 6; ++i)
#pragma unroll
        for (int l = 0; l < 3; ++l) pk[10 + i * 3 + l] = Kf[i][l];
    f32x4* pd = (f32x4*)(pack + (size_t)n * 28);
#pragma unroll
    for (int q = 0; q < 7; ++q) {
        f32x4 v = {pk[q * 4 + 0], pk[q * 4 + 1], pk[q * 4 + 2], pk[q * 4 + 3]};
        pd[q] = v;
    }
}

// Replicate task w: read 4 float4 of stage once, nt-store to all M slices.
__device__ __forceinline__ void replicate_task(const float* __restrict__ stage,
                                               float* __restrict__ covs,
                                               const int* __restrict__ mask32,
                                               const unsigned char* __restrict__ mask8,
                                               int N, int M, int w) {
    int total4 = N * 9;
    const f32x4* s4 = (const f32x4*)stage;
    f32x4* base = (f32x4*)covs;
    int i0 = w * 1024 + (int)threadIdx.x;
    f32x4 z = {0.f, 0.f, 0.f, 0.f};
    f32x4 v[4];
    int idx[4];
    bool ok[4];
#pragma unroll
    for (int k = 0; k < 4; ++k) {
        idx[k] = i0 + k * 256;
        ok[k] = idx[k] < total4;
        v[k] = ok[k] ? s4[idx[k]] : z;
    }
    for (int m = 0; m < M; ++m) {
        bool mk = mask_true(mask32, mask8, m);
        f32x4* d4 = base + (size_t)m * total4;
#pragma unroll
        for (int k = 0; k < 4; ++k)
            if (ok[k]) __builtin_nontemporal_store(mk ? v[k] : z, d4 + idx[k]);
    }
}

// Update task u: GROUP_M measurements for one 256-particle chunk.
__device__ __forceinline__ void update_task(const float* __restrict__ means,
                                            const float* __restrict__ meas,
                                            const int* __restrict__ mask32,
                                            const unsigned char* __restrict__ mask8,
                                            const float* __restrict__ pack,
                                            float* __restrict__ pts,
                                            float* __restrict__ logw,
                                            int N, int M, int UBx,
                                            float* __restrict__ spts, int u) {
    int mg = u / UBx;
    int nb = u - mg * UBx;
    int n0 = nb * 256;
    int count = N - n0;
    if (count > 256) count = 256;
    int nloc = threadIdx.x;
    int n = n0 + nloc;

    float hx0 = 0, hx1 = 0, hx2 = 0, logdet = 0;
    float L00 = 1, L10 = 0, L11 = 1, L20 = 0, L21 = 0, L22 = 1;
    float K[18];
    float x[6];
    if (nloc < count) {
        const f32x4* pk4 = (const f32x4*)(pack + (size_t)n * 28);
        f32x4 q0 = pk4[0], q1 = pk4[1], q2 = pk4[2], q3 = pk4[3];
        f32x4 q4 = pk4[4], q5 = pk4[5], q6 = pk4[6];
        hx0 = q0.x; hx1 = q0.y; hx2 = q0.z; logdet = q0.w;
        L00 = q1.x; L10 = q1.y; L11 = q1.z; L20 = q1.w;
        L21 = q2.x; L22 = q2.y;
        K[0] = q2.z; K[1] = q2.w; K[2] = q3.x; K[3] = q3.y; K[4] = q3.z; K[5] = q3.w;
        K[6] = q4.x; K[7] = q4.y; K[8] = q4.z; K[9] = q4.w; K[10] = q5.x; K[11] = q5.y;
        K[12] = q5.z; K[13] = q5.w; K[14] = q6.x; K[15] = q6.y; K[16] = q6.z; K[17] = q6.w;
        const float2* mm = (const float2*)(means + (size_t)n * 6);
        float2 ma = mm[0], mb2 = mm[1], mc = mm[2];
        x[0] = ma.x; x[1] = ma.y; x[2] = mb2.x; x[3] = mb2.y; x[4] = mc.x; x[5] = mc.y;
    }

#pragma unroll
    for (int j = 0; j < GROUP_M; ++j) {
        int m = mg * GROUP_M + j;
        if (m >= M) break;  // uniform across block
        bool mk = mask_true(mask32, mask8, m);
        __syncthreads();  // spts reuse guard
        if (nloc < count) {
            float pt[6];
            if (mk) {
                float z0 = meas[m * 3 + 0];
                float z1 = meas[m * 3 + 1];
                float z2v = meas[m * 3 + 2];
                float i0 = hx0 - z0, i1 = hx1 - z1, i2 = hx2 - z2v;
#pragma unroll
                for (int d = 0; d < 6; ++d)
                    pt[d] = x[d] - (K[d * 3 + 0] * i0 + K[d * 3 + 1] * i1 + K[d * 3 + 2] * i2);
                float px = pt[0], py = pt[1], pz = pt[2];
                float r2 = px * px + py * py + pz * pz;
                float rho = sqrtf(r2);
                float d0 = z0 - rho;
                float d1 = z1 - atan2f(py, px);
                float d2 = z2v - asinf(pz / rho);
                float y0 = d0 / L00;
                float y1 = (d1 - L10 * y0) / L11;
                float y2 = (d2 - L20 * y0 - L21 * y1) / L22;
                float quad = y0 * y0 + y1 * y1 + y2 * y2;
                __builtin_nontemporal_store(-0.5f * quad - logdet - 2.7568156f,
                                            &logw[(size_t)m * N + n]);  // 1.5*log(2pi)
            } else {
#pragma unroll
                for (int d = 0; d < 6; ++d) pt[d] = 0.f;
                __builtin_nontemporal_store(-INFINITY, &logw[(size_t)m * N + n]);
            }
#pragma unroll
            for (int d = 0; d < 6; ++d) spts[nloc * 6 + d] = pt[d];
        }
        __syncthreads();
        int nf = count * 6;
        float* dst = pts + ((size_t)m * N + n0) * 6;
        const f32x4* s4 = (const f32x4*)spts;
        f32x4* d4 = (f32x4*)dst;
        int n4 = nf >> 2;
        for (int i = (int)threadIdx.x; i < n4; i += 256)
            __builtin_nontemporal_store(s4[i], d4 + i);
        for (int i = (n4 << 2) + (int)threadIdx.x; i < nf; i += 256)
            dst[i] = spts[i];
    }
}

// ---------- cooperative mega kernel ----------

__global__ __launch_bounds__(256, 4) void mega_kernel(const float* __restrict__ means,
                                                      const float* __restrict__ meas,
                                                      const int* __restrict__ mask32,
                                                      const unsigned char* __restrict__ mask8,
                                                      const float* __restrict__ Rin,
                                                      double* __restrict__ partials,
                                                      float* __restrict__ pack,
                                                      float* __restrict__ stage,
                                                      float* __restrict__ pts,
                                                      float* __restrict__ logw,
                                                      float* __restrict__ covs,
                                                      int N, int M, int RB, int UBx,
                                                      int totalTasks) {
    cg::grid_group grid = cg::this_grid();
    __shared__ double sStats[27];
    __shared__ double sP[36];
    __shared__ float sPf[36];
    __shared__ float spts[6 * 256];

    // Phase A: stat partials
    if ((int)blockIdx.x < NB_STATS)
        stats_body(means, N, partials, NB_STATS);

    grid.sync();

    // Phase C: particle precompute (grid-stride; each active block builds P)
    for (int base = blockIdx.x * 256; base < N; base += gridDim.x * 256) {
        build_P_block(partials, N, sStats, sP, sPf);
        int n = base + (int)threadIdx.x;
        if (n < N) particle_body(means, Rin, sP, sPf, stage, pack, n);
        __syncthreads();
    }

    grid.sync();

    // Phase D: output tasks (replicate tasks first for load balance)
    for (int w = blockIdx.x; w < totalTasks; w += gridDim.x) {
        if (w < RB)
            replicate_task(stage, covs, mask32, mask8, N, M, w);
        else
            update_task(means, meas, mask32, mask8, pack, pts, logw, N, M, UBx, spts, w - RB);
        __syncthreads();
    }
}

// ---------- fallback kernels (round-4 path) ----------

__global__ __launch_bounds__(256) void stats_partial_kernel(const float* __restrict__ means,
                                                            int N, double* __restrict__ partials) {
    stats_body(means, N, partials, NB_STATS);
}

__global__ __launch_bounds__(256) void particle_kernel(const float* __restrict__ means,
                                                       const float* __restrict__ Rin,
                                                       const double* __restrict__ partials,
                                                       float* __restrict__ stage,
                                                       float* __restrict__ pack,
                                                       int N) {
    __shared__ double sStats[27];
    __shared__ double sP[36];
    __shared__ float sPf[36];
    build_P_block(partials, N, sStats, sP, sPf);
    int n = blockIdx.x * blockDim.x + threadIdx.x;
    if (n < N) particle_body(means, Rin, sP, sPf, stage, pack, n);
}

__global__ __launch_bounds__(256) void fused_out_kernel(const float* __restrict__ means,
                                                        const float* __restrict__ meas,
                                                        const int* __restrict__ mask32,
                                                        const unsigned char* __restrict__ mask8,
                                                        const float* __restrict__ pack,
                                                        const float* __restrict__ stage,
                                                        float* __restrict__ pts,
                                                        float* __restrict__ logw,
                                                        float* __restrict__ covs,
                                                        int N, int M, int RB, int UBx) {
    __shared__ float spts[6 * 256];
    int b = blockIdx.x;
    if (b < RB)
        replicate_task(stage, covs, mask32, mask8, N, M, b);
    else
        update_task(means, meas, mask32, mask8, pack, pts, logw, N, M, UBx, spts, b - RB);
}

extern "C" void kernel_launch(void* const* d_in, const int* in_sizes, int n_in,
                              void* d_out, int out_size, void* d_ws, size_t ws_size,
                              hipStream_t stream) {
    const float* means = (const float*)d_in[0];
    const float* meas = (const float*)d_in[3];
    const int* mask32 = (const int*)d_in[4];
    const unsigned char* mask8 = (const unsigned char*)d_in[4];
    const float* Rin = (const float*)d_in[5];

    int N = in_sizes[0] / NDIM;
    int M = in_sizes[3] / MDIM;

    float* out = (float*)d_out;
    float* pts = out;                               // [M,N,6]
    float* logw = out + (size_t)M * N * 6;          // [M,N]
    float* covs = out + (size_t)M * N * 7;          // [M,N,6,6]

    double* ws = (double*)d_ws;
    double* partials = ws;                               // 27*NB_STATS f64
    float* pack = (float*)(ws + 27 * NB_STATS);          // N*28 f32
    float* stage = pack + (size_t)N * 28;                // N*36 f32
    size_t need_full = 27 * NB_STATS * sizeof(double) +
                       (size_t)N * (28 + 36) * sizeof(float);

    int UBx = (N + 255) / 256;
    int MG = (M + GROUP_M - 1) / GROUP_M;
    int RB = (N * 9 + 1023) / 1024;
    int totalTasks = RB + UBx * MG;

    bool coop_ok = false;
    int grid = 0;
    if (ws_size >= need_full) {
        int dev = 0;
        if (hipGetDevice(&dev) == hipSuccess) {
            int coopAttr = 0;
            int numCU = 0;
            int maxBpcu = 0;
            hipError_t e1 = hipDeviceGetAttribute(&coopAttr,
                                                  hipDeviceAttributeCooperativeLaunch, dev);
            hipError_t e2 = hipDeviceGetAttribute(&numCU,
                                                  hipDeviceAttributeMultiprocessorCount, dev);
            hipError_t e3 = hipOccupancyMaxActiveBlocksPerMultiprocessor(
                &maxBpcu, (const void*)mega_kernel, 256, 0);
            if (e1 == hipSuccess && e2 == hipSuccess && e3 == hipSuccess &&
                coopAttr && maxBpcu > 0 && numCU > 0) {
                long long maxGrid = (long long)maxBpcu * numCU;
                long long g = totalTasks;
                if (g > maxGrid) g = maxGrid;
                if (g >= NB_STATS) {
                    grid = (int)g;
                    coop_ok = true;
                }
            }
        }
    }

    if (coop_ok) {
        void* args[] = {(void*)&means, (void*)&meas, (void*)&mask32, (void*)&mask8,
                        (void*)&Rin,   (void*)&partials, (void*)&pack, (void*)&stage,
                        (void*)&pts,   (void*)&logw,  (void*)&covs,
                        (void*)&N,     (void*)&M,     (void*)&RB, (void*)&UBx,
                        (void*)&totalTasks};
        if (hipLaunchCooperativeKernel((const void*)mega_kernel, dim3(grid), dim3(256),
                                       args, 0, stream) == hipSuccess)
            return;
    }

    // Fallback: 3-kernel round-4 path (requires ws for pack+stage; previous
    // rounds confirmed ws is large enough in this harness).
    stats_partial_kernel<<<NB_STATS, 256, 0, stream>>>(means, N, partials);
    particle_kernel<<<UBx, 256, 0, stream>>>(means, Rin, partials, stage, pack, N);
    fused_out_kernel<<<RB + UBx * MG, 256, 0, stream>>>(means, meas, mask32, mask8, pack,
                                                        stage, pts, logw, covs, N, M, RB, UBx);
}

// Round 7
// 82.479 us; speedup vs baseline: 2.2151x; 2.2151x over previous
//
#include <hip/hip_runtime.h>
#include <math.h>

// EnGMPHD update kernel for MI355X (round 7).
// Revert cooperative experiment (regression: coop co-residency + grid.sync
// cut streaming-store BW to 1.2 TB/s). Round-4 3-kernel pipeline with:
//   - replicate chunks split MSPLIT=4 ways (1760 replicate blocks, each reads
//     a 16 KB chunk once and writes 8 of 32 slices) for store concurrency
//   - regular stores everywhere (harness fill proves 6.87 TB/s, no RFO)
//
//   1. stats_partial_kernel: 128 blocks, per-block partial sums (stat-major)
//   2. particle_kernel: reduce partials -> P (LDS); per-particle
//      H/S/Chol/Sinv/K (f32 transcendentals, f64 algebra) -> stage+pack (ws)
//   3. fused_out_kernel: replicate tasks then update tasks (GROUP_M=8)

#define NDIM 6
#define MDIM 3
#define NB_STATS 128
#define GROUP_M 8
#define MSPLIT 4
typedef float f32x4 __attribute__((ext_vector_type(4)));

__device__ __forceinline__ bool mask_true(const int* m32, const unsigned char* m8, int m) {
    return (m32[m] != 0) || (m8[m] != 0);
}

__global__ __launch_bounds__(256) void stats_partial_kernel(const float* __restrict__ means,
                                                            int N, double* __restrict__ partials) {
    double sx[6];
    double sxx[21];
#pragma unroll
    for (int i = 0; i < 6; ++i) sx[i] = 0.0;
#pragma unroll
    for (int i = 0; i < 21; ++i) sxx[i] = 0.0;

    int stride = NB_STATS * 256;
    for (int n = blockIdx.x * 256 + threadIdx.x; n < N; n += stride) {
        const float2* mp = (const float2*)(means + (size_t)n * 6);
        float2 a = mp[0], b = mp[1], c = mp[2];
        double x[6] = {a.x, a.y, b.x, b.y, c.x, c.y};
        int p = 0;
#pragma unroll
        for (int i = 0; i < 6; ++i) {
            sx[i] += x[i];
#pragma unroll
            for (int j = i; j < 6; ++j) sxx[p++] += x[i] * x[j];
        }
    }
#pragma unroll
    for (int off = 32; off >= 1; off >>= 1) {
#pragma unroll
        for (int i = 0; i < 6; ++i) sx[i] += __shfl_down(sx[i], off);
#pragma unroll
        for (int i = 0; i < 21; ++i) sxx[i] += __shfl_down(sxx[i], off);
    }
    __shared__ double lds[4][27];
    int wave = threadIdx.x >> 6;
    if ((threadIdx.x & 63) == 0) {
#pragma unroll
        for (int i = 0; i < 6; ++i) lds[wave][i] = sx[i];
#pragma unroll
        for (int i = 0; i < 21; ++i) lds[wave][6 + i] = sxx[i];
    }
    __syncthreads();
    if (threadIdx.x < 27) {
        double v = lds[0][threadIdx.x] + lds[1][threadIdx.x] +
                   lds[2][threadIdx.x] + lds[3][threadIdx.x];
        partials[threadIdx.x * NB_STATS + blockIdx.x] = v;
    }
}

// Reduce partials (threads 0..26) + build P (thread 0) into sP/sPf. Caller syncs.
__device__ __forceinline__ void build_P_block(const double* __restrict__ partials, int N,
                                              double* __restrict__ sStats,
                                              double* __restrict__ sP,
                                              float* __restrict__ sPf) {
    if (threadIdx.x < 27) {
        const double* src = partials + (size_t)threadIdx.x * NB_STATS;
        double acc = 0.0;
#pragma unroll 8
        for (int b = 0; b < NB_STATS; ++b) acc += src[b];
        sStats[threadIdx.x] = acc;
    }
    __syncthreads();
    if (threadIdx.x == 0) {
        double mean[6];
#pragma unroll
        for (int i = 0; i < 6; ++i) mean[i] = sStats[i] / (double)N;
        double bandwidth = pow(4.0 / ((double)N * 8.0), 0.2);  // d=6
        int p = 0;
        for (int i = 0; i < 6; ++i) {
            for (int j = i; j < 6; ++j) {
                double emp = (sStats[6 + p] - (double)N * mean[i] * mean[j]) / (double)(N - 1);
                double dd = (double)(j - i);
                double val = bandwidth * emp * exp(-(dd * dd) / 18.0);  // L = 3.0
                sP[i * 6 + j] = val;
                sP[j * 6 + i] = val;
                ++p;
            }
        }
    }
    __syncthreads();
    if (threadIdx.x < 36) sPf[threadIdx.x] = (float)sP[threadIdx.x];
    __syncthreads();
}

__global__ __launch_bounds__(256) void particle_kernel(const float* __restrict__ means,
                                                       const float* __restrict__ Rin,
                                                       const double* __restrict__ partials,
                                                       float* __restrict__ stage,
                                                       float* __restrict__ pack,
                                                       int N) {
    __shared__ double sStats[27];
    __shared__ double sP[36];
    __shared__ float sPf[36];
    build_P_block(partials, N, sStats, sP, sPf);

    int n = blockIdx.x * blockDim.x + threadIdx.x;
    if (n >= N) return;

    const float2* mp = (const float2*)(means + (size_t)n * 6);
    float2 ma = mp[0], mb = mp[1];
    float px = ma.x, py = ma.y, pz = mb.x;
    float s2 = px * px + py * py;
    float r2 = s2 + pz * pz;
    float rho = sqrtf(r2);
    float s = sqrtf(s2);
    float hx0 = rho;
    float hx1 = atan2f(py, px);
    float hx2 = asinf(pz / rho);
    float H[3][3];
    H[0][0] = px / rho; H[0][1] = py / rho; H[0][2] = pz / rho;
    H[1][0] = -py / s2; H[1][1] = px / s2;  H[1][2] = 0.0f;
    float invr2s = 1.0f / (r2 * s);
    H[2][0] = -pz * px * invr2s; H[2][1] = -pz * py * invr2s; H[2][2] = s / r2;

    double T[3][3];
#pragma unroll
    for (int i = 0; i < 3; ++i)
#pragma unroll
        for (int k = 0; k < 3; ++k)
            T[i][k] = (double)H[i][0] * sP[0 * 6 + k] + (double)H[i][1] * sP[1 * 6 + k] +
                      (double)H[i][2] * sP[2 * 6 + k];
    double S[3][3];
#pragma unroll
    for (int i = 0; i < 3; ++i)
#pragma unroll
        for (int l = 0; l < 3; ++l)
            S[i][l] = T[i][0] * (double)H[l][0] + T[i][1] * (double)H[l][1] +
                      T[i][2] * (double)H[l][2] + (double)Rin[i * 3 + l];

    double L00 = sqrt(S[0][0]);
    double L10 = S[1][0] / L00;
    double L20 = S[2][0] / L00;
    double L11 = sqrt(S[1][1] - L10 * L10);
    double L21 = (S[2][1] - L20 * L10) / L11;
    double L22 = sqrt(S[2][2] - L20 * L20 - L21 * L21);
    float logdet = logf((float)(L00 * L11 * L22));

    double a00 = S[0][0], a01 = S[0][1], a02 = S[0][2];
    double a11 = S[1][1], a12 = S[1][2], a22 = S[2][2];
    double c00 = a11 * a22 - a12 * a12;
    double c01 = a02 * a12 - a01 * a22;
    double c02 = a01 * a12 - a02 * a11;
    double c11 = a00 * a22 - a02 * a02;
    double c12 = a01 * a02 - a00 * a12;
    double c22 = a00 * a11 - a01 * a01;
    double invdet = 1.0 / (a00 * c00 + a01 * c01 + a02 * c02);
    double Si[3][3] = {{c00 * invdet, c01 * invdet, c02 * invdet},
                       {c01 * invdet, c11 * invdet, c12 * invdet},
                       {c02 * invdet, c12 * invdet, c22 * invdet}};

    float Kf[6][3];
#pragma unroll
    for (int i = 0; i < 6; ++i) {
        double pht[3];
#pragma unroll
        for (int k = 0; k < 3; ++k)
            pht[k] = sP[i * 6 + 0] * (double)H[k][0] + sP[i * 6 + 1] * (double)H[k][1] +
                     sP[i * 6 + 2] * (double)H[k][2];
#pragma unroll
        for (int l = 0; l < 3; ++l)
            Kf[i][l] = (float)(pht[0] * Si[0][l] + pht[1] * Si[1][l] + pht[2] * Si[2][l]);
    }

    float KH[6][3];
#pragma unroll
    for (int i = 0; i < 6; ++i)
#pragma unroll
        for (int j = 0; j < 3; ++j)
            KH[i][j] = Kf[i][0] * H[0][j] + Kf[i][1] * H[1][j] + Kf[i][2] * H[2][j];
    float cp[36];
#pragma unroll
    for (int i = 0; i < 6; ++i)
#pragma unroll
        for (int j = 0; j < 6; ++j)
            cp[i * 6 + j] = sPf[i * 6 + j] - (KH[i][0] * sPf[0 * 6 + j] +
                                              KH[i][1] * sPf[1 * 6 + j] +
                                              KH[i][2] * sPf[2 * 6 + j]);
    f32x4* dst = (f32x4*)(stage + (size_t)n * 36);
#pragma unroll
    for (int q = 0; q < 9; ++q) {
        f32x4 v = {cp[q * 4 + 0], cp[q * 4 + 1], cp[q * 4 + 2], cp[q * 4 + 3]};
        dst[q] = v;
    }

    float pk[28];
    pk[0] = hx0; pk[1] = hx1; pk[2] = hx2; pk[3] = logdet;
    pk[4] = (float)L00; pk[5] = (float)L10; pk[6] = (float)L11;
    pk[7] = (float)L20; pk[8] = (float)L21; pk[9] = (float)L22;
#pragma unroll
    for (int i = 0; i < 6; ++i)
#pragma unroll
        for (int l = 0; l < 3; ++l) pk[10 + i * 3 + l] = Kf[i][l];
    f32x4* pd = (f32x4*)(pack + (size_t)n * 28);
#pragma unroll
    for (int q = 0; q < 7; ++q) {
        f32x4 v = {pk[q * 4 + 0], pk[q * 4 + 1], pk[q * 4 + 2], pk[q * 4 + 3]};
        pd[q] = v;
    }
}

// Replicate task: chunk c = w/MSPLIT, group g = w%MSPLIT. Read 4 float4 of
// stage once; write slices m = g, g+MSPLIT, ... (8 slices for M=32).
__device__ __forceinline__ void replicate_task(const float* __restrict__ stage,
                                               float* __restrict__ covs,
                                               const int* __restrict__ mask32,
                                               const unsigned char* __restrict__ mask8,
                                               int N, int M, int w) {
    int c = w / MSPLIT;
    int g = w - c * MSPLIT;
    int total4 = N * 9;
    const f32x4* s4 = (const f32x4*)stage;
    f32x4* base = (f32x4*)covs;
    int i0 = c * 1024 + (int)threadIdx.x;
    f32x4 z = {0.f, 0.f, 0.f, 0.f};
    f32x4 v[4];
    int idx[4];
    bool ok[4];
#pragma unroll
    for (int k = 0; k < 4; ++k) {
        idx[k] = i0 + k * 256;
        ok[k] = idx[k] < total4;
        v[k] = ok[k] ? s4[idx[k]] : z;
    }
    for (int m = g; m < M; m += MSPLIT) {
        bool mk = mask_true(mask32, mask8, m);
        f32x4* d4 = base + (size_t)m * total4;
#pragma unroll
        for (int k = 0; k < 4; ++k)
            if (ok[k]) d4[idx[k]] = mk ? v[k] : z;
    }
}

// Update task u: GROUP_M measurements for one 256-particle chunk.
__device__ __forceinline__ void update_task(const float* __restrict__ means,
                                            const float* __restrict__ meas,
                                            const int* __restrict__ mask32,
                                            const unsigned char* __restrict__ mask8,
                                            const float* __restrict__ pack,
                                            float* __restrict__ pts,
                                            float* __restrict__ logw,
                                            int N, int M, int UBx,
                                            float* __restrict__ spts, int u) {
    int mg = u / UBx;
    int nb = u - mg * UBx;
    int n0 = nb * 256;
    int count = N - n0;
    if (count > 256) count = 256;
    int nloc = threadIdx.x;
    int n = n0 + nloc;

    float hx0 = 0, hx1 = 0, hx2 = 0, logdet = 0;
    float L00 = 1, L10 = 0, L11 = 1, L20 = 0, L21 = 0, L22 = 1;
    float K[18];
    float x[6];
    if (nloc < count) {
        const f32x4* pk4 = (const f32x4*)(pack + (size_t)n * 28);
        f32x4 q0 = pk4[0], q1 = pk4[1], q2 = pk4[2], q3 = pk4[3];
        f32x4 q4 = pk4[4], q5 = pk4[5], q6 = pk4[6];
        hx0 = q0.x; hx1 = q0.y; hx2 = q0.z; logdet = q0.w;
        L00 = q1.x; L10 = q1.y; L11 = q1.z; L20 = q1.w;
        L21 = q2.x; L22 = q2.y;
        K[0] = q2.z; K[1] = q2.w; K[2] = q3.x; K[3] = q3.y; K[4] = q3.z; K[5] = q3.w;
        K[6] = q4.x; K[7] = q4.y; K[8] = q4.z; K[9] = q4.w; K[10] = q5.x; K[11] = q5.y;
        K[12] = q5.z; K[13] = q5.w; K[14] = q6.x; K[15] = q6.y; K[16] = q6.z; K[17] = q6.w;
        const float2* mm = (const float2*)(means + (size_t)n * 6);
        float2 ma = mm[0], mb2 = mm[1], mc = mm[2];
        x[0] = ma.x; x[1] = ma.y; x[2] = mb2.x; x[3] = mb2.y; x[4] = mc.x; x[5] = mc.y;
    }

#pragma unroll
    for (int j = 0; j < GROUP_M; ++j) {
        int m = mg * GROUP_M + j;
        if (m >= M) break;  // uniform across block
        bool mk = mask_true(mask32, mask8, m);
        __syncthreads();  // spts reuse guard
        if (nloc < count) {
            float pt[6];
            if (mk) {
                float z0 = meas[m * 3 + 0];
                float z1 = meas[m * 3 + 1];
                float z2v = meas[m * 3 + 2];
                float i0 = hx0 - z0, i1 = hx1 - z1, i2 = hx2 - z2v;
#pragma unroll
                for (int d = 0; d < 6; ++d)
                    pt[d] = x[d] - (K[d * 3 + 0] * i0 + K[d * 3 + 1] * i1 + K[d * 3 + 2] * i2);
                float px = pt[0], py = pt[1], pz = pt[2];
                float r2 = px * px + py * py + pz * pz;
                float rho = sqrtf(r2);
                float d0 = z0 - rho;
                float d1 = z1 - atan2f(py, px);
                float d2 = z2v - asinf(pz / rho);
                float y0 = d0 / L00;
                float y1 = (d1 - L10 * y0) / L11;
                float y2 = (d2 - L20 * y0 - L21 * y1) / L22;
                float quad = y0 * y0 + y1 * y1 + y2 * y2;
                logw[(size_t)m * N + n] = -0.5f * quad - logdet - 2.7568156f;  // 1.5*log(2pi)
            } else {
#pragma unroll
                for (int d = 0; d < 6; ++d) pt[d] = 0.f;
                logw[(size_t)m * N + n] = -INFINITY;
            }
#pragma unroll
            for (int d = 0; d < 6; ++d) spts[nloc * 6 + d] = pt[d];
        }
        __syncthreads();
        int nf = count * 6;
        float* dst = pts + ((size_t)m * N + n0) * 6;
        const f32x4* s4 = (const f32x4*)spts;
        f32x4* d4 = (f32x4*)dst;
        int n4 = nf >> 2;
        for (int i = (int)threadIdx.x; i < n4; i += 256)
            d4[i] = s4[i];
        for (int i = (n4 << 2) + (int)threadIdx.x; i < nf; i += 256)
            dst[i] = spts[i];
    }
}

__global__ __launch_bounds__(256) void fused_out_kernel(const float* __restrict__ means,
                                                        const float* __restrict__ meas,
                                                        const int* __restrict__ mask32,
                                                        const unsigned char* __restrict__ mask8,
                                                        const float* __restrict__ pack,
                                                        const float* __restrict__ stage,
                                                        float* __restrict__ pts,
                                                        float* __restrict__ logw,
                                                        float* __restrict__ covs,
                                                        int N, int M, int RBS, int UBx) {
    __shared__ float spts[6 * 256];
    int b = blockIdx.x;
    if (b < RBS)
        replicate_task(stage, covs, mask32, mask8, N, M, b);
    else
        update_task(means, meas, mask32, mask8, pack, pts, logw, N, M, UBx, spts, b - RBS);
}

// Fallback replicate (stage aliases covs slice 0): read-before-write per thread.
__global__ __launch_bounds__(256) void replicate_loop_kernel(const float* __restrict__ stage,
                                                             float* __restrict__ covs,
                                                             const int* __restrict__ mask32,
                                                             const unsigned char* __restrict__ mask8,
                                                             int N, int M) {
    int idx = blockIdx.x * blockDim.x + threadIdx.x;
    int total4 = N * 9;
    if (idx >= total4) return;
    const f32x4* s4 = (const f32x4*)stage;
    f32x4* base = (f32x4*)covs;
    f32x4 v = s4[idx];
    f32x4 z = {0.f, 0.f, 0.f, 0.f};
    for (int m = 0; m < M; ++m) {
        bool mk = mask_true(mask32, mask8, m);
        base[(size_t)m * total4 + idx] = mk ? v : z;
    }
}

extern "C" void kernel_launch(void* const* d_in, const int* in_sizes, int n_in,
                              void* d_out, int out_size, void* d_ws, size_t ws_size,
                              hipStream_t stream) {
    const float* means = (const float*)d_in[0];
    const float* meas = (const float*)d_in[3];
    const int* mask32 = (const int*)d_in[4];
    const unsigned char* mask8 = (const unsigned char*)d_in[4];
    const float* Rin = (const float*)d_in[5];

    int N = in_sizes[0] / NDIM;
    int M = in_sizes[3] / MDIM;

    float* out = (float*)d_out;
    float* pts = out;                               // [M,N,6]
    float* logw = out + (size_t)M * N * 6;          // [M,N]
    float* covs = out + (size_t)M * N * 7;          // [M,N,6,6]

    double* ws = (double*)d_ws;
    double* partials = ws;                               // 27*NB_STATS f64
    float* pack = (float*)(ws + 27 * NB_STATS);          // N*28 f32
    float* stage = pack + (size_t)N * 28;                // N*36 f32
    size_t need_full = 27 * NB_STATS * sizeof(double) +
                       (size_t)N * (28 + 36) * sizeof(float);

    int UBx = (N + 255) / 256;
    int MG = (M + GROUP_M - 1) / GROUP_M;
    int RB = (N * 9 + 1023) / 1024;   // 16KB chunks

    stats_partial_kernel<<<NB_STATS, 256, 0, stream>>>(means, N, partials);

    if (ws_size >= need_full) {
        particle_kernel<<<UBx, 256, 0, stream>>>(means, Rin, partials, stage, pack, N);
        int RBS = RB * MSPLIT;
        fused_out_kernel<<<RBS + UBx * MG, 256, 0, stream>>>(
            means, meas, mask32, mask8, pack, stage, pts, logw, covs, N, M, RBS, UBx);
    } else {
        // Fallback: stage in covs slice 0; update-only fused + loop replicate.
        particle_kernel<<<UBx, 256, 0, stream>>>(means, Rin, partials, covs, pack, N);
        fused_out_kernel<<<UBx * MG, 256, 0, stream>>>(
            means, meas, mask32, mask8, pack, covs, pts, logw, covs, N, M, 0, UBx);
        replicate_loop_kernel<<<RB * 4, 256, 0, stream>>>(covs, covs, mask32, mask8, N, M);
    }
}

// Round 8
// 78.744 us; speedup vs baseline: 2.3202x; 1.0474x over previous
//
#include <hip/hip_runtime.h>
#include <math.h>

// EnGMPHD update kernel for MI355X (round 8).
// 2-kernel pipeline; per-particle work recomputed in-register inside the
// output kernel (VALU is ~5% busy — recompute is free under the store stream):
//   1. stats_partial_kernel: 128 blocks, per-block partial sums (stat-major)
//   2. fused_all_kernel:
//      - every block: reduce partials -> P in LDS (27KB L2 read, f64)
//      - covs-role blocks (nb,g): per-thread H/S/Chol/Sinv/K -> covs_post ->
//        LDS [256][36] -> stream 4 contiguous 36KB slices (m = g::8)
//      - update-role blocks (mg,nb): per-thread pack in registers, then
//        GROUP_M=4 m's of pts (LDS repack -> contiguous float4) + logw
// No stage/pack buffers, no third kernel, no dependency drains between
// particle precompute and output.

#define NDIM 6
#define MDIM 3
#define NB_STATS 128
#define MSPLIT 8   // covs-role: each block writes M/MSPLIT = 4 slices
#define GROUP_M 4  // update-role: m's per block
typedef float f32x4 __attribute__((ext_vector_type(4)));

__device__ __forceinline__ bool mask_true(const int* m32, const unsigned char* m8, int m) {
    return (m32[m] != 0) || (m8[m] != 0);
}

__global__ __launch_bounds__(256) void stats_partial_kernel(const float* __restrict__ means,
                                                            int N, double* __restrict__ partials) {
    double sx[6];
    double sxx[21];
#pragma unroll
    for (int i = 0; i < 6; ++i) sx[i] = 0.0;
#pragma unroll
    for (int i = 0; i < 21; ++i) sxx[i] = 0.0;

    int stride = NB_STATS * 256;
    for (int n = blockIdx.x * 256 + threadIdx.x; n < N; n += stride) {
        const float2* mp = (const float2*)(means + (size_t)n * 6);
        float2 a = mp[0], b = mp[1], c = mp[2];
        double x[6] = {a.x, a.y, b.x, b.y, c.x, c.y};
        int p = 0;
#pragma unroll
        for (int i = 0; i < 6; ++i) {
            sx[i] += x[i];
#pragma unroll
            for (int j = i; j < 6; ++j) sxx[p++] += x[i] * x[j];
        }
    }
#pragma unroll
    for (int off = 32; off >= 1; off >>= 1) {
#pragma unroll
        for (int i = 0; i < 6; ++i) sx[i] += __shfl_down(sx[i], off);
#pragma unroll
        for (int i = 0; i < 21; ++i) sxx[i] += __shfl_down(sxx[i], off);
    }
    __shared__ double lds[4][27];
    int wave = threadIdx.x >> 6;
    if ((threadIdx.x & 63) == 0) {
#pragma unroll
        for (int i = 0; i < 6; ++i) lds[wave][i] = sx[i];
#pragma unroll
        for (int i = 0; i < 21; ++i) lds[wave][6 + i] = sxx[i];
    }
    __syncthreads();
    if (threadIdx.x < 27) {
        double v = lds[0][threadIdx.x] + lds[1][threadIdx.x] +
                   lds[2][threadIdx.x] + lds[3][threadIdx.x];
        partials[threadIdx.x * NB_STATS + blockIdx.x] = v;
    }
}

// Reduce partials (threads 0..26) + build P (thread 0) into sP/sPf. Syncs inside.
__device__ __forceinline__ void build_P_block(const double* __restrict__ partials, int N,
                                              double* __restrict__ sStats,
                                              double* __restrict__ sP,
                                              float* __restrict__ sPf) {
    if (threadIdx.x < 27) {
        const double* src = partials + (size_t)threadIdx.x * NB_STATS;
        double acc = 0.0;
#pragma unroll 8
        for (int b = 0; b < NB_STATS; ++b) acc += src[b];
        sStats[threadIdx.x] = acc;
    }
    __syncthreads();
    if (threadIdx.x == 0) {
        double mean[6];
#pragma unroll
        for (int i = 0; i < 6; ++i) mean[i] = sStats[i] / (double)N;
        double bandwidth = pow(4.0 / ((double)N * 8.0), 0.2);  // d=6
        int p = 0;
        for (int i = 0; i < 6; ++i) {
            for (int j = i; j < 6; ++j) {
                double emp = (sStats[6 + p] - (double)N * mean[i] * mean[j]) / (double)(N - 1);
                double dd = (double)(j - i);
                double val = bandwidth * emp * exp(-(dd * dd) / 18.0);  // L = 3.0
                sP[i * 6 + j] = val;
                sP[j * 6 + i] = val;
                ++p;
            }
        }
    }
    __syncthreads();
    if (threadIdx.x < 36) sPf[threadIdx.x] = (float)sP[threadIdx.x];
    __syncthreads();
}

struct PData {
    float hx0, hx1, hx2, logdet;
    float L00, L10, L11, L20, L21, L22;
    float Kf[6][3];
    float H[3][3];
};

// Per-particle measurement-model pipeline: f32 transcendentals, f64 algebra.
__device__ __forceinline__ void particle_compute(const float* __restrict__ means,
                                                 const float* __restrict__ Rin,
                                                 const double* __restrict__ sP,
                                                 int n, float* __restrict__ x, PData& o) {
    const float2* mp = (const float2*)(means + (size_t)n * 6);
    float2 ma = mp[0], mb = mp[1], mc = mp[2];
    x[0] = ma.x; x[1] = ma.y; x[2] = mb.x; x[3] = mb.y; x[4] = mc.x; x[5] = mc.y;
    float px = ma.x, py = ma.y, pz = mb.x;
    float s2 = px * px + py * py;
    float r2 = s2 + pz * pz;
    float rho = sqrtf(r2);
    float s = sqrtf(s2);
    o.hx0 = rho;
    o.hx1 = atan2f(py, px);
    o.hx2 = asinf(pz / rho);
    o.H[0][0] = px / rho; o.H[0][1] = py / rho; o.H[0][2] = pz / rho;
    o.H[1][0] = -py / s2; o.H[1][1] = px / s2;  o.H[1][2] = 0.0f;
    float invr2s = 1.0f / (r2 * s);
    o.H[2][0] = -pz * px * invr2s; o.H[2][1] = -pz * py * invr2s; o.H[2][2] = s / r2;

    double T[3][3];
#pragma unroll
    for (int i = 0; i < 3; ++i)
#pragma unroll
        for (int k = 0; k < 3; ++k)
            T[i][k] = (double)o.H[i][0] * sP[0 * 6 + k] + (double)o.H[i][1] * sP[1 * 6 + k] +
                      (double)o.H[i][2] * sP[2 * 6 + k];
    double S[3][3];
#pragma unroll
    for (int i = 0; i < 3; ++i)
#pragma unroll
        for (int l = 0; l < 3; ++l)
            S[i][l] = T[i][0] * (double)o.H[l][0] + T[i][1] * (double)o.H[l][1] +
                      T[i][2] * (double)o.H[l][2] + (double)Rin[i * 3 + l];

    double L00 = sqrt(S[0][0]);
    double L10 = S[1][0] / L00;
    double L20 = S[2][0] / L00;
    double L11 = sqrt(S[1][1] - L10 * L10);
    double L21 = (S[2][1] - L20 * L10) / L11;
    double L22 = sqrt(S[2][2] - L20 * L20 - L21 * L21);
    o.L00 = (float)L00; o.L10 = (float)L10; o.L11 = (float)L11;
    o.L20 = (float)L20; o.L21 = (float)L21; o.L22 = (float)L22;
    o.logdet = logf((float)(L00 * L11 * L22));

    double a00 = S[0][0], a01 = S[0][1], a02 = S[0][2];
    double a11 = S[1][1], a12 = S[1][2], a22 = S[2][2];
    double c00 = a11 * a22 - a12 * a12;
    double c01 = a02 * a12 - a01 * a22;
    double c02 = a01 * a12 - a02 * a11;
    double c11 = a00 * a22 - a02 * a02;
    double c12 = a01 * a02 - a00 * a12;
    double c22 = a00 * a11 - a01 * a01;
    double invdet = 1.0 / (a00 * c00 + a01 * c01 + a02 * c02);
    double Si[3][3] = {{c00 * invdet, c01 * invdet, c02 * invdet},
                       {c01 * invdet, c11 * invdet, c12 * invdet},
                       {c02 * invdet, c12 * invdet, c22 * invdet}};

#pragma unroll
    for (int i = 0; i < 6; ++i) {
        double pht[3];
#pragma unroll
        for (int k = 0; k < 3; ++k)
            pht[k] = sP[i * 6 + 0] * (double)o.H[k][0] + sP[i * 6 + 1] * (double)o.H[k][1] +
                     sP[i * 6 + 2] * (double)o.H[k][2];
#pragma unroll
        for (int l = 0; l < 3; ++l)
            o.Kf[i][l] = (float)(pht[0] * Si[0][l] + pht[1] * Si[1][l] + pht[2] * Si[2][l]);
    }
}

// grid = CB + UB blocks.
//   b <  CB: covs role.  b = nb*MSPLIT + g: particles nb*256.., slices m=g::MSPLIT
//   b >= CB: update role. u = mg*UBx + nb: GROUP_M m's, particles nb*256..
__global__ __launch_bounds__(256) void fused_all_kernel(const float* __restrict__ means,
                                                        const float* __restrict__ meas,
                                                        const int* __restrict__ mask32,
                                                        const unsigned char* __restrict__ mask8,
                                                        const float* __restrict__ Rin,
                                                        const double* __restrict__ partials,
                                                        float* __restrict__ pts,
                                                        float* __restrict__ logw,
                                                        float* __restrict__ covs,
                                                        int N, int M, int CB, int UBx) {
    __shared__ double sStats[27];
    __shared__ double sP[36];
    __shared__ float sPf[36];
    __shared__ float sbuf[256 * 36];  // covs tile; update role uses first 6KB

    build_P_block(partials, N, sStats, sP, sPf);

    int b = blockIdx.x;
    int tid = threadIdx.x;

    if (b < CB) {
        // ---------------- covs role ----------------
        int nb = b / MSPLIT;
        int g = b - nb * MSPLIT;
        int n0 = nb * 256;
        int count = N - n0;
        if (count > 256) count = 256;

        if (tid < count) {
            float x[6];
            PData o;
            particle_compute(means, Rin, sP, n0 + tid, x, o);
            // covs_post = (I - K H) P  (f32)
            float KH[6][3];
#pragma unroll
            for (int i = 0; i < 6; ++i)
#pragma unroll
                for (int j = 0; j < 3; ++j)
                    KH[i][j] = o.Kf[i][0] * o.H[0][j] + o.Kf[i][1] * o.H[1][j] +
                               o.Kf[i][2] * o.H[2][j];
            float* row = sbuf + tid * 36;
#pragma unroll
            for (int i = 0; i < 6; ++i)
#pragma unroll
                for (int j = 0; j < 6; ++j)
                    row[i * 6 + j] = sPf[i * 6 + j] - (KH[i][0] * sPf[0 * 6 + j] +
                                                       KH[i][1] * sPf[1 * 6 + j] +
                                                       KH[i][2] * sPf[2 * 6 + j]);
        }
        __syncthreads();

        int nf4 = count * 9;  // float4s in this tile
        const f32x4* s4 = (const f32x4*)sbuf;
        f32x4 z = {0.f, 0.f, 0.f, 0.f};
        for (int m = g; m < M; m += MSPLIT) {
            bool mk = mask_true(mask32, mask8, m);
            f32x4* d4 = (f32x4*)covs + ((size_t)m * N + n0) * 9;
            if (mk) {
                for (int i = tid; i < nf4; i += 256) d4[i] = s4[i];
            } else {
                for (int i = tid; i < nf4; i += 256) d4[i] = z;
            }
        }
        return;
    }

    // ---------------- update role ----------------
    int u = b - CB;
    int mg = u / UBx;
    int nb = u - mg * UBx;
    int n0 = nb * 256;
    int count = N - n0;
    if (count > 256) count = 256;

    float x[6];
    PData o;
    if (tid < count) particle_compute(means, Rin, sP, n0 + tid, x, o);

#pragma unroll
    for (int j = 0; j < GROUP_M; ++j) {
        int m = mg * GROUP_M + j;
        if (m >= M) break;  // uniform across block
        bool mk = mask_true(mask32, mask8, m);
        __syncthreads();  // sbuf reuse guard
        if (tid < count) {
            float pt[6];
            if (mk) {
                float z0 = meas[m * 3 + 0];
                float z1 = meas[m * 3 + 1];
                float z2v = meas[m * 3 + 2];
                float i0 = o.hx0 - z0, i1 = o.hx1 - z1, i2 = o.hx2 - z2v;
#pragma unroll
                for (int d = 0; d < 6; ++d)
                    pt[d] = x[d] - (o.Kf[d][0] * i0 + o.Kf[d][1] * i1 + o.Kf[d][2] * i2);
                float px = pt[0], py = pt[1], pz = pt[2];
                float r2 = px * px + py * py + pz * pz;
                float rho = sqrtf(r2);
                float d0 = z0 - rho;
                float d1 = z1 - atan2f(py, px);
                float d2 = z2v - asinf(pz / rho);
                float y0 = d0 / o.L00;
                float y1 = (d1 - o.L10 * y0) / o.L11;
                float y2 = (d2 - o.L20 * y0 - o.L21 * y1) / o.L22;
                float quad = y0 * y0 + y1 * y1 + y2 * y2;
                logw[(size_t)m * N + n0 + tid] = -0.5f * quad - o.logdet - 2.7568156f;
            } else {
#pragma unroll
                for (int d = 0; d < 6; ++d) pt[d] = 0.f;
                logw[(size_t)m * N + n0 + tid] = -INFINITY;
            }
#pragma unroll
            for (int d = 0; d < 6; ++d) sbuf[tid * 6 + d] = pt[d];
        }
        __syncthreads();
        int nf = count * 6;
        float* dst = pts + ((size_t)m * N + n0) * 6;
        const f32x4* s4 = (const f32x4*)sbuf;
        f32x4* d4 = (f32x4*)dst;
        int n4 = nf >> 2;
        for (int i = tid; i < n4; i += 256) d4[i] = s4[i];
        for (int i = (n4 << 2) + tid; i < nf; i += 256) dst[i] = sbuf[i];
    }
}

extern "C" void kernel_launch(void* const* d_in, const int* in_sizes, int n_in,
                              void* d_out, int out_size, void* d_ws, size_t ws_size,
                              hipStream_t stream) {
    const float* means = (const float*)d_in[0];
    const float* meas = (const float*)d_in[3];
    const int* mask32 = (const int*)d_in[4];
    const unsigned char* mask8 = (const unsigned char*)d_in[4];
    const float* Rin = (const float*)d_in[5];

    int N = in_sizes[0] / NDIM;
    int M = in_sizes[3] / MDIM;

    float* out = (float*)d_out;
    float* pts = out;                               // [M,N,6]
    float* logw = out + (size_t)M * N * 6;          // [M,N]
    float* covs = out + (size_t)M * N * 7;          // [M,N,6,6]

    double* partials = (double*)d_ws;               // 27*NB_STATS f64 (27 KB)

    int UBx = (N + 255) / 256;
    int MG = (M + GROUP_M - 1) / GROUP_M;
    int CB = UBx * MSPLIT;       // covs-role blocks
    int UB = UBx * MG;           // update-role blocks

    stats_partial_kernel<<<NB_STATS, 256, 0, stream>>>(means, N, partials);
    fused_all_kernel<<<CB + UB, 256, 0, stream>>>(means, meas, mask32, mask8, Rin,
                                                  partials, pts, logw, covs, N, M, CB, UBx);
}

// Round 9
// 68.572 us; speedup vs baseline: 2.6644x; 1.1483x over previous
//
#include <hip/hip_runtime.h>
#include <math.h>

// EnGMPHD update kernel for MI355X (round 9).
// 3-launch pipeline (third launch is 1 tiny block):
//   1. stats_partial_kernel: 128 blocks, per-block partial sums (stat-major)
//   2. computeP_kernel: 1 block, tree-reduce partials + build P -> ws P64[36]
//   3. fused_all_kernel: every block loads P (36 f64, one cache line);
//      - covs-role blocks (c,g): 128 particles -> H/S/Chol/Sinv/K -> covs_post
//        -> LDS [128][36] (18 KB => 8 blocks/CU) -> stream slices m=g::8
//      - update-role blocks (mg,nb): per-thread pack in registers, then
//        GROUP_M=4 m's of pts (LDS repack -> contiguous float4) + logw

#define NDIM 6
#define MDIM 3
#define NB_STATS 128
#define MSPLIT 8   // covs-role: each block writes M/MSPLIT = 4 slices
#define GROUP_M 4  // update-role: m's per block
#define CHUNK 128  // covs-role particles per block (18 KB LDS tile)
typedef float f32x4 __attribute__((ext_vector_type(4)));

__device__ __forceinline__ bool mask_true(const int* m32, const unsigned char* m8, int m) {
    return (m32[m] != 0) || (m8[m] != 0);
}

__global__ __launch_bounds__(256) void stats_partial_kernel(const float* __restrict__ means,
                                                            int N, double* __restrict__ partials) {
    double sx[6];
    double sxx[21];
#pragma unroll
    for (int i = 0; i < 6; ++i) sx[i] = 0.0;
#pragma unroll
    for (int i = 0; i < 21; ++i) sxx[i] = 0.0;

    int stride = NB_STATS * 256;
    for (int n = blockIdx.x * 256 + threadIdx.x; n < N; n += stride) {
        const float2* mp = (const float2*)(means + (size_t)n * 6);
        float2 a = mp[0], b = mp[1], c = mp[2];
        double x[6] = {a.x, a.y, b.x, b.y, c.x, c.y};
        int p = 0;
#pragma unroll
        for (int i = 0; i < 6; ++i) {
            sx[i] += x[i];
#pragma unroll
            for (int j = i; j < 6; ++j) sxx[p++] += x[i] * x[j];
        }
    }
#pragma unroll
    for (int off = 32; off >= 1; off >>= 1) {
#pragma unroll
        for (int i = 0; i < 6; ++i) sx[i] += __shfl_down(sx[i], off);
#pragma unroll
        for (int i = 0; i < 21; ++i) sxx[i] += __shfl_down(sxx[i], off);
    }
    __shared__ double lds[4][27];
    int wave = threadIdx.x >> 6;
    if ((threadIdx.x & 63) == 0) {
#pragma unroll
        for (int i = 0; i < 6; ++i) lds[wave][i] = sx[i];
#pragma unroll
        for (int i = 0; i < 21; ++i) lds[wave][6 + i] = sxx[i];
    }
    __syncthreads();
    if (threadIdx.x < 27) {
        double v = lds[0][threadIdx.x] + lds[1][threadIdx.x] +
                   lds[2][threadIdx.x] + lds[3][threadIdx.x];
        partials[threadIdx.x * NB_STATS + blockIdx.x] = v;
    }
}

// One block: tree-reduce partials (8 threads per stat x 16 each) + build P.
__global__ __launch_bounds__(256) void computeP_kernel(const double* __restrict__ partials,
                                                       int N, double* __restrict__ P64) {
    __shared__ double red[27][8];
    int tid = threadIdx.x;
    int s = tid >> 3, j = tid & 7;
    if (s < 27) {
        const double* src = partials + (size_t)s * NB_STATS + j * 16;
        double acc = 0.0;
#pragma unroll
        for (int k = 0; k < 16; ++k) acc += src[k];
        red[s][j] = acc;
    }
    __syncthreads();
    if (tid < 27) {
        double a = 0.0;
#pragma unroll
        for (int q = 0; q < 8; ++q) a += red[tid][q];
        red[tid][0] = a;
    }
    __syncthreads();
    if (tid == 0) {
        double mean[6];
#pragma unroll
        for (int i = 0; i < 6; ++i) mean[i] = red[i][0] / (double)N;
        double bandwidth = pow(4.0 / ((double)N * 8.0), 0.2);  // (4/(n(d+2)))^(2/(d+4)), d=6
        int p = 0;
        for (int i = 0; i < 6; ++i) {
            for (int jj = i; jj < 6; ++jj) {
                double emp = (red[6 + p][0] - (double)N * mean[i] * mean[jj]) / (double)(N - 1);
                double dd = (double)(jj - i);
                double val = bandwidth * emp * exp(-(dd * dd) / 18.0);  // L = 3.0
                P64[i * 6 + jj] = val;
                P64[jj * 6 + i] = val;
                ++p;
            }
        }
    }
}

struct PData {
    float hx0, hx1, hx2, logdet;
    float L00, L10, L11, L20, L21, L22;
    float Kf[6][3];
    float H[3][3];
};

// Per-particle measurement-model pipeline: f32 transcendentals, f64 algebra.
__device__ __forceinline__ void particle_compute(const float* __restrict__ means,
                                                 const float* __restrict__ Rin,
                                                 const double* __restrict__ sP,
                                                 int n, float* __restrict__ x, PData& o) {
    const float2* mp = (const float2*)(means + (size_t)n * 6);
    float2 ma = mp[0], mb = mp[1], mc = mp[2];
    x[0] = ma.x; x[1] = ma.y; x[2] = mb.x; x[3] = mb.y; x[4] = mc.x; x[5] = mc.y;
    float px = ma.x, py = ma.y, pz = mb.x;
    float s2 = px * px + py * py;
    float r2 = s2 + pz * pz;
    float rho = sqrtf(r2);
    float s = sqrtf(s2);
    o.hx0 = rho;
    o.hx1 = atan2f(py, px);
    o.hx2 = asinf(pz / rho);
    o.H[0][0] = px / rho; o.H[0][1] = py / rho; o.H[0][2] = pz / rho;
    o.H[1][0] = -py / s2; o.H[1][1] = px / s2;  o.H[1][2] = 0.0f;
    float invr2s = 1.0f / (r2 * s);
    o.H[2][0] = -pz * px * invr2s; o.H[2][1] = -pz * py * invr2s; o.H[2][2] = s / r2;

    double T[3][3];
#pragma unroll
    for (int i = 0; i < 3; ++i)
#pragma unroll
        for (int k = 0; k < 3; ++k)
            T[i][k] = (double)o.H[i][0] * sP[0 * 6 + k] + (double)o.H[i][1] * sP[1 * 6 + k] +
                      (double)o.H[i][2] * sP[2 * 6 + k];
    double S[3][3];
#pragma unroll
    for (int i = 0; i < 3; ++i)
#pragma unroll
        for (int l = 0; l < 3; ++l)
            S[i][l] = T[i][0] * (double)o.H[l][0] + T[i][1] * (double)o.H[l][1] +
                      T[i][2] * (double)o.H[l][2] + (double)Rin[i * 3 + l];

    double L00 = sqrt(S[0][0]);
    double L10 = S[1][0] / L00;
    double L20 = S[2][0] / L00;
    double L11 = sqrt(S[1][1] - L10 * L10);
    double L21 = (S[2][1] - L20 * L10) / L11;
    double L22 = sqrt(S[2][2] - L20 * L20 - L21 * L21);
    o.L00 = (float)L00; o.L10 = (float)L10; o.L11 = (float)L11;
    o.L20 = (float)L20; o.L21 = (float)L21; o.L22 = (float)L22;
    o.logdet = logf((float)(L00 * L11 * L22));

    double a00 = S[0][0], a01 = S[0][1], a02 = S[0][2];
    double a11 = S[1][1], a12 = S[1][2], a22 = S[2][2];
    double c00 = a11 * a22 - a12 * a12;
    double c01 = a02 * a12 - a01 * a22;
    double c02 = a01 * a12 - a02 * a11;
    double c11 = a00 * a22 - a02 * a02;
    double c12 = a01 * a02 - a00 * a12;
    double c22 = a00 * a11 - a01 * a01;
    double invdet = 1.0 / (a00 * c00 + a01 * c01 + a02 * c02);
    double Si[3][3] = {{c00 * invdet, c01 * invdet, c02 * invdet},
                       {c01 * invdet, c11 * invdet, c12 * invdet},
                       {c02 * invdet, c12 * invdet, c22 * invdet}};

#pragma unroll
    for (int i = 0; i < 6; ++i) {
        double pht[3];
#pragma unroll
        for (int k = 0; k < 3; ++k)
            pht[k] = sP[i * 6 + 0] * (double)o.H[k][0] + sP[i * 6 + 1] * (double)o.H[k][1] +
                     sP[i * 6 + 2] * (double)o.H[k][2];
#pragma unroll
        for (int l = 0; l < 3; ++l)
            o.Kf[i][l] = (float)(pht[0] * Si[0][l] + pht[1] * Si[1][l] + pht[2] * Si[2][l]);
    }
}

// grid = CB + UB blocks.
//   b <  CB: covs role.  b = c*MSPLIT + g: particles c*CHUNK.., slices m=g::MSPLIT
//   b >= CB: update role. u = mg*UBx + nb: GROUP_M m's, particles nb*256..
__global__ __launch_bounds__(256) void fused_all_kernel(const float* __restrict__ means,
                                                        const float* __restrict__ meas,
                                                        const int* __restrict__ mask32,
                                                        const unsigned char* __restrict__ mask8,
                                                        const float* __restrict__ Rin,
                                                        const double* __restrict__ P64,
                                                        float* __restrict__ pts,
                                                        float* __restrict__ logw,
                                                        float* __restrict__ covs,
                                                        int N, int M, int CB, int UBx) {
    __shared__ double sP[36];
    __shared__ float sPf[36];
    __shared__ float sbuf[CHUNK * 36];  // 18 KB: covs tile; update role uses first 6 KB

    int tid = threadIdx.x;
    if (tid < 36) {
        double v = P64[tid];
        sP[tid] = v;
        sPf[tid] = (float)v;
    }
    __syncthreads();

    int b = blockIdx.x;

    if (b < CB) {
        // ---------------- covs role ----------------
        int c = b / MSPLIT;
        int g = b - c * MSPLIT;
        int n0 = c * CHUNK;
        int count = N - n0;
        if (count > CHUNK) count = CHUNK;

        if (tid < count) {
            float x[6];
            PData o;
            particle_compute(means, Rin, sP, n0 + tid, x, o);
            float KH[6][3];
#pragma unroll
            for (int i = 0; i < 6; ++i)
#pragma unroll
                for (int j = 0; j < 3; ++j)
                    KH[i][j] = o.Kf[i][0] * o.H[0][j] + o.Kf[i][1] * o.H[1][j] +
                               o.Kf[i][2] * o.H[2][j];
            float* row = sbuf + tid * 36;
#pragma unroll
            for (int i = 0; i < 6; ++i)
#pragma unroll
                for (int j = 0; j < 6; ++j)
                    row[i * 6 + j] = sPf[i * 6 + j] - (KH[i][0] * sPf[0 * 6 + j] +
                                                       KH[i][1] * sPf[1 * 6 + j] +
                                                       KH[i][2] * sPf[2 * 6 + j]);
        }
        __syncthreads();

        int nf4 = count * 9;  // float4s in this tile
        const f32x4* s4 = (const f32x4*)sbuf;
        f32x4 z = {0.f, 0.f, 0.f, 0.f};
        for (int m = g; m < M; m += MSPLIT) {
            bool mk = mask_true(mask32, mask8, m);
            f32x4* d4 = (f32x4*)covs + ((size_t)m * N + n0) * 9;
            if (mk) {
                for (int i = tid; i < nf4; i += 256) d4[i] = s4[i];
            } else {
                for (int i = tid; i < nf4; i += 256) d4[i] = z;
            }
        }
        return;
    }

    // ---------------- update role ----------------
    int u = b - CB;
    int mg = u / UBx;
    int nb = u - mg * UBx;
    int n0 = nb * 256;
    int count = N - n0;
    if (count > 256) count = 256;

    float x[6];
    PData o;
    if (tid < count) particle_compute(means, Rin, sP, n0 + tid, x, o);

#pragma unroll
    for (int j = 0; j < GROUP_M; ++j) {
        int m = mg * GROUP_M + j;
        if (m >= M) break;  // uniform across block
        bool mk = mask_true(mask32, mask8, m);
        __syncthreads();  // sbuf reuse guard
        if (tid < count) {
            float pt[6];
            if (mk) {
                float z0 = meas[m * 3 + 0];
                float z1 = meas[m * 3 + 1];
                float z2v = meas[m * 3 + 2];
                float i0 = o.hx0 - z0, i1 = o.hx1 - z1, i2 = o.hx2 - z2v;
#pragma unroll
                for (int d = 0; d < 6; ++d)
                    pt[d] = x[d] - (o.Kf[d][0] * i0 + o.Kf[d][1] * i1 + o.Kf[d][2] * i2);
                float px = pt[0], py = pt[1], pz = pt[2];
                float r2 = px * px + py * py + pz * pz;
                float rho = sqrtf(r2);
                float d0 = z0 - rho;
                float d1 = z1 - atan2f(py, px);
                float d2 = z2v - asinf(pz / rho);
                float y0 = d0 / o.L00;
                float y1 = (d1 - o.L10 * y0) / o.L11;
                float y2 = (d2 - o.L20 * y0 - o.L21 * y1) / o.L22;
                float quad = y0 * y0 + y1 * y1 + y2 * y2;
                logw[(size_t)m * N + n0 + tid] = -0.5f * quad - o.logdet - 2.7568156f;
            } else {
#pragma unroll
                for (int d = 0; d < 6; ++d) pt[d] = 0.f;
                logw[(size_t)m * N + n0 + tid] = -INFINITY;
            }
#pragma unroll
            for (int d = 0; d < 6; ++d) sbuf[tid * 6 + d] = pt[d];
        }
        __syncthreads();
        int nf = count * 6;
        float* dst = pts + ((size_t)m * N + n0) * 6;
        const f32x4* s4 = (const f32x4*)sbuf;
        f32x4* d4 = (f32x4*)dst;
        int n4 = nf >> 2;
        for (int i = tid; i < n4; i += 256) d4[i] = s4[i];
        for (int i = (n4 << 2) + tid; i < nf; i += 256) dst[i] = sbuf[i];
    }
}

extern "C" void kernel_launch(void* const* d_in, const int* in_sizes, int n_in,
                              void* d_out, int out_size, void* d_ws, size_t ws_size,
                              hipStream_t stream) {
    const float* means = (const float*)d_in[0];
    const float* meas = (const float*)d_in[3];
    const int* mask32 = (const int*)d_in[4];
    const unsigned char* mask8 = (const unsigned char*)d_in[4];
    const float* Rin = (const float*)d_in[5];

    int N = in_sizes[0] / NDIM;
    int M = in_sizes[3] / MDIM;

    float* out = (float*)d_out;
    float* pts = out;                               // [M,N,6]
    float* logw = out + (size_t)M * N * 6;          // [M,N]
    float* covs = out + (size_t)M * N * 7;          // [M,N,6,6]

    double* partials = (double*)d_ws;               // 27*NB_STATS f64 (27 KB)
    double* P64 = partials + 27 * NB_STATS;         // 36 f64

    int UBx = (N + 255) / 256;
    int MG = (M + GROUP_M - 1) / GROUP_M;
    int NC = (N + CHUNK - 1) / CHUNK;
    int CB = NC * MSPLIT;        // covs-role blocks
    int UB = UBx * MG;           // update-role blocks

    stats_partial_kernel<<<NB_STATS, 256, 0, stream>>>(means, N, partials);
    computeP_kernel<<<1, 256, 0, stream>>>(partials, N, P64);
    fused_all_kernel<<<CB + UB, 256, 0, stream>>>(means, meas, mask32, mask8, Rin,
                                                  P64, pts, logw, covs, N, M, CB, UBx);
}

// Round 10
// 65.159 us; speedup vs baseline: 2.8040x; 1.0524x over previous
//
#include <hip/hip_runtime.h>
#include <math.h>

// EnGMPHD update kernel for MI355X (round 10).
// Round-9 pipeline + Bresenham-striped roles in fused_all (covs and update
// blocks interleaved across the dispatch order so the update role's
// compute-heavy, store-light blocks hide under the covs store stream
// instead of forming a low-BW tail phase).
//   1. stats_partial_kernel: 128 blocks, per-block partial sums (stat-major)
//   2. computeP_kernel: 1 block, tree-reduce partials + build P -> ws P64[36]
//   3. fused_all_kernel (striped roles):
//      - covs role (c,g): 128 particles -> H/S/Chol/Sinv/K -> covs_post ->
//        LDS [128][36] (18 KB, 8 blocks/CU = wave cap) -> slices m=g::8
//      - update role (mg,nb): pack in registers, GROUP_M=4 m's of pts
//        (LDS repack -> contiguous float4) + logw

#define NDIM 6
#define MDIM 3
#define NB_STATS 128
#define MSPLIT 8   // covs role: each block writes M/MSPLIT = 4 slices
#define GROUP_M 4  // update role: m's per block
#define CHUNK 128  // covs role particles per block (18 KB LDS tile)
typedef float f32x4 __attribute__((ext_vector_type(4)));

__device__ __forceinline__ bool mask_true(const int* m32, const unsigned char* m8, int m) {
    return (m32[m] != 0) || (m8[m] != 0);
}

__global__ __launch_bounds__(256) void stats_partial_kernel(const float* __restrict__ means,
                                                            int N, double* __restrict__ partials) {
    double sx[6];
    double sxx[21];
#pragma unroll
    for (int i = 0; i < 6; ++i) sx[i] = 0.0;
#pragma unroll
    for (int i = 0; i < 21; ++i) sxx[i] = 0.0;

    int stride = NB_STATS * 256;
    for (int n = blockIdx.x * 256 + threadIdx.x; n < N; n += stride) {
        const float2* mp = (const float2*)(means + (size_t)n * 6);
        float2 a = mp[0], b = mp[1], c = mp[2];
        double x[6] = {a.x, a.y, b.x, b.y, c.x, c.y};
        int p = 0;
#pragma unroll
        for (int i = 0; i < 6; ++i) {
            sx[i] += x[i];
#pragma unroll
            for (int j = i; j < 6; ++j) sxx[p++] += x[i] * x[j];
        }
    }
#pragma unroll
    for (int off = 32; off >= 1; off >>= 1) {
#pragma unroll
        for (int i = 0; i < 6; ++i) sx[i] += __shfl_down(sx[i], off);
#pragma unroll
        for (int i = 0; i < 21; ++i) sxx[i] += __shfl_down(sxx[i], off);
    }
    __shared__ double lds[4][27];
    int wave = threadIdx.x >> 6;
    if ((threadIdx.x & 63) == 0) {
#pragma unroll
        for (int i = 0; i < 6; ++i) lds[wave][i] = sx[i];
#pragma unroll
        for (int i = 0; i < 21; ++i) lds[wave][6 + i] = sxx[i];
    }
    __syncthreads();
    if (threadIdx.x < 27) {
        double v = lds[0][threadIdx.x] + lds[1][threadIdx.x] +
                   lds[2][threadIdx.x] + lds[3][threadIdx.x];
        partials[threadIdx.x * NB_STATS + blockIdx.x] = v;
    }
}

// One block: tree-reduce partials (8 threads per stat x 16 each) + build P.
__global__ __launch_bounds__(256) void computeP_kernel(const double* __restrict__ partials,
                                                       int N, double* __restrict__ P64) {
    __shared__ double red[27][8];
    int tid = threadIdx.x;
    int s = tid >> 3, j = tid & 7;
    if (s < 27) {
        const double* src = partials + (size_t)s * NB_STATS + j * 16;
        double acc = 0.0;
#pragma unroll
        for (int k = 0; k < 16; ++k) acc += src[k];
        red[s][j] = acc;
    }
    __syncthreads();
    if (tid < 27) {
        double a = 0.0;
#pragma unroll
        for (int q = 0; q < 8; ++q) a += red[tid][q];
        red[tid][0] = a;
    }
    __syncthreads();
    if (tid == 0) {
        double mean[6];
#pragma unroll
        for (int i = 0; i < 6; ++i) mean[i] = red[i][0] / (double)N;
        double bandwidth = pow(4.0 / ((double)N * 8.0), 0.2);  // (4/(n(d+2)))^(2/(d+4)), d=6
        int p = 0;
        for (int i = 0; i < 6; ++i) {
            for (int jj = i; jj < 6; ++jj) {
                double emp = (red[6 + p][0] - (double)N * mean[i] * mean[jj]) / (double)(N - 1);
                double dd = (double)(jj - i);
                double val = bandwidth * emp * exp(-(dd * dd) / 18.0);  // L = 3.0
                P64[i * 6 + jj] = val;
                P64[jj * 6 + i] = val;
                ++p;
            }
        }
    }
}

struct PData {
    float hx0, hx1, hx2, logdet;
    float L00, L10, L11, L20, L21, L22;
    float Kf[6][3];
    float H[3][3];
};

// Per-particle measurement-model pipeline: f32 transcendentals, f64 algebra.
__device__ __forceinline__ void particle_compute(const float* __restrict__ means,
                                                 const float* __restrict__ Rin,
                                                 const double* __restrict__ sP,
                                                 int n, float* __restrict__ x, PData& o) {
    const float2* mp = (const float2*)(means + (size_t)n * 6);
    float2 ma = mp[0], mb = mp[1], mc = mp[2];
    x[0] = ma.x; x[1] = ma.y; x[2] = mb.x; x[3] = mb.y; x[4] = mc.x; x[5] = mc.y;
    float px = ma.x, py = ma.y, pz = mb.x;
    float s2 = px * px + py * py;
    float r2 = s2 + pz * pz;
    float rho = sqrtf(r2);
    float s = sqrtf(s2);
    o.hx0 = rho;
    o.hx1 = atan2f(py, px);
    o.hx2 = asinf(pz / rho);
    o.H[0][0] = px / rho; o.H[0][1] = py / rho; o.H[0][2] = pz / rho;
    o.H[1][0] = -py / s2; o.H[1][1] = px / s2;  o.H[1][2] = 0.0f;
    float invr2s = 1.0f / (r2 * s);
    o.H[2][0] = -pz * px * invr2s; o.H[2][1] = -pz * py * invr2s; o.H[2][2] = s / r2;

    double T[3][3];
#pragma unroll
    for (int i = 0; i < 3; ++i)
#pragma unroll
        for (int k = 0; k < 3; ++k)
            T[i][k] = (double)o.H[i][0] * sP[0 * 6 + k] + (double)o.H[i][1] * sP[1 * 6 + k] +
                      (double)o.H[i][2] * sP[2 * 6 + k];
    double S[3][3];
#pragma unroll
    for (int i = 0; i < 3; ++i)
#pragma unroll
        for (int l = 0; l < 3; ++l)
            S[i][l] = T[i][0] * (double)o.H[l][0] + T[i][1] * (double)o.H[l][1] +
                      T[i][2] * (double)o.H[l][2] + (double)Rin[i * 3 + l];

    double L00 = sqrt(S[0][0]);
    double L10 = S[1][0] / L00;
    double L20 = S[2][0] / L00;
    double L11 = sqrt(S[1][1] - L10 * L10);
    double L21 = (S[2][1] - L20 * L10) / L11;
    double L22 = sqrt(S[2][2] - L20 * L20 - L21 * L21);
    o.L00 = (float)L00; o.L10 = (float)L10; o.L11 = (float)L11;
    o.L20 = (float)L20; o.L21 = (float)L21; o.L22 = (float)L22;
    o.logdet = logf((float)(L00 * L11 * L22));

    double a00 = S[0][0], a01 = S[0][1], a02 = S[0][2];
    double a11 = S[1][1], a12 = S[1][2], a22 = S[2][2];
    double c00 = a11 * a22 - a12 * a12;
    double c01 = a02 * a12 - a01 * a22;
    double c02 = a01 * a12 - a02 * a11;
    double c11 = a00 * a22 - a02 * a02;
    double c12 = a01 * a02 - a00 * a12;
    double c22 = a00 * a11 - a01 * a01;
    double invdet = 1.0 / (a00 * c00 + a01 * c01 + a02 * c02);
    double Si[3][3] = {{c00 * invdet, c01 * invdet, c02 * invdet},
                       {c01 * invdet, c11 * invdet, c12 * invdet},
                       {c02 * invdet, c12 * invdet, c22 * invdet}};

#pragma unroll
    for (int i = 0; i < 6; ++i) {
        double pht[3];
#pragma unroll
        for (int k = 0; k < 3; ++k)
            pht[k] = sP[i * 6 + 0] * (double)o.H[k][0] + sP[i * 6 + 1] * (double)o.H[k][1] +
                     sP[i * 6 + 2] * (double)o.H[k][2];
#pragma unroll
        for (int l = 0; l < 3; ++l)
            o.Kf[i][l] = (float)(pht[0] * Si[0][l] + pht[1] * Si[1][l] + pht[2] * Si[2][l]);
    }
}

// Roles striped via Bresenham: covs tasks CB, update tasks UB, TB = CB+UB.
//   cbef = b*CB/TB; if ((b+1)*CB/TB > cbef) -> covs task cbef
//   else -> update task (b - cbef)
__global__ __launch_bounds__(256) void fused_all_kernel(const float* __restrict__ means,
                                                        const float* __restrict__ meas,
                                                        const int* __restrict__ mask32,
                                                        const unsigned char* __restrict__ mask8,
                                                        const float* __restrict__ Rin,
                                                        const double* __restrict__ P64,
                                                        float* __restrict__ pts,
                                                        float* __restrict__ logw,
                                                        float* __restrict__ covs,
                                                        int N, int M, int CB, int TB,
                                                        int UBx) {
    __shared__ double sP[36];
    __shared__ float sPf[36];
    __shared__ float sbuf[CHUNK * 36];  // 18 KB: covs tile; update role uses first 6 KB

    int tid = threadIdx.x;
    if (tid < 36) {
        double v = P64[tid];
        sP[tid] = v;
        sPf[tid] = (float)v;
    }
    __syncthreads();

    long long b = blockIdx.x;
    int cbef = (int)(b * CB / TB);
    int cnext = (int)((b + 1) * CB / TB);

    if (cnext > cbef) {
        // ---------------- covs role (task cbef) ----------------
        int c = cbef / MSPLIT;
        int g = cbef - c * MSPLIT;
        int n0 = c * CHUNK;
        int count = N - n0;
        if (count > CHUNK) count = CHUNK;

        if (tid < count) {
            float x[6];
            PData o;
            particle_compute(means, Rin, sP, n0 + tid, x, o);
            float KH[6][3];
#pragma unroll
            for (int i = 0; i < 6; ++i)
#pragma unroll
                for (int j = 0; j < 3; ++j)
                    KH[i][j] = o.Kf[i][0] * o.H[0][j] + o.Kf[i][1] * o.H[1][j] +
                               o.Kf[i][2] * o.H[2][j];
            float* row = sbuf + tid * 36;
#pragma unroll
            for (int i = 0; i < 6; ++i)
#pragma unroll
                for (int j = 0; j < 6; ++j)
                    row[i * 6 + j] = sPf[i * 6 + j] - (KH[i][0] * sPf[0 * 6 + j] +
                                                       KH[i][1] * sPf[1 * 6 + j] +
                                                       KH[i][2] * sPf[2 * 6 + j]);
        }
        __syncthreads();

        int nf4 = count * 9;  // float4s in this tile
        const f32x4* s4 = (const f32x4*)sbuf;
        f32x4 z = {0.f, 0.f, 0.f, 0.f};
        for (int m = g; m < M; m += MSPLIT) {
            bool mk = mask_true(mask32, mask8, m);
            f32x4* d4 = (f32x4*)covs + ((size_t)m * N + n0) * 9;
            if (mk) {
                for (int i = tid; i < nf4; i += 256) d4[i] = s4[i];
            } else {
                for (int i = tid; i < nf4; i += 256) d4[i] = z;
            }
        }
        return;
    }

    // ---------------- update role (task b - cbef) ----------------
    int u = (int)(b - cbef);
    int mg = u / UBx;
    int nb = u - mg * UBx;
    int n0 = nb * 256;
    int count = N - n0;
    if (count > 256) count = 256;

    float x[6];
    PData o;
    if (tid < count) particle_compute(means, Rin, sP, n0 + tid, x, o);

#pragma unroll
    for (int j = 0; j < GROUP_M; ++j) {
        int m = mg * GROUP_M + j;
        if (m >= M) break;  // uniform across block
        bool mk = mask_true(mask32, mask8, m);
        __syncthreads();  // sbuf reuse guard
        if (tid < count) {
            float pt[6];
            if (mk) {
                float z0 = meas[m * 3 + 0];
                float z1 = meas[m * 3 + 1];
                float z2v = meas[m * 3 + 2];
                float i0 = o.hx0 - z0, i1 = o.hx1 - z1, i2 = o.hx2 - z2v;
#pragma unroll
                for (int d = 0; d < 6; ++d)
                    pt[d] = x[d] - (o.Kf[d][0] * i0 + o.Kf[d][1] * i1 + o.Kf[d][2] * i2);
                float px = pt[0], py = pt[1], pz = pt[2];
                float r2 = px * px + py * py + pz * pz;
                float rho = sqrtf(r2);
                float d0 = z0 - rho;
                float d1 = z1 - atan2f(py, px);
                float d2 = z2v - asinf(pz / rho);
                float y0 = d0 / o.L00;
                float y1 = (d1 - o.L10 * y0) / o.L11;
                float y2 = (d2 - o.L20 * y0 - o.L21 * y1) / o.L22;
                float quad = y0 * y0 + y1 * y1 + y2 * y2;
                logw[(size_t)m * N + n0 + tid] = -0.5f * quad - o.logdet - 2.7568156f;
            } else {
#pragma unroll
                for (int d = 0; d < 6; ++d) pt[d] = 0.f;
                logw[(size_t)m * N + n0 + tid] = -INFINITY;
            }
#pragma unroll
            for (int d = 0; d < 6; ++d) sbuf[tid * 6 + d] = pt[d];
        }
        __syncthreads();
        int nf = count * 6;
        float* dst = pts + ((size_t)m * N + n0) * 6;
        const f32x4* s4 = (const f32x4*)sbuf;
        f32x4* d4 = (f32x4*)dst;
        int n4 = nf >> 2;
        for (int i = tid; i < n4; i += 256) d4[i] = s4[i];
        for (int i = (n4 << 2) + tid; i < nf; i += 256) dst[i] = sbuf[i];
    }
}

extern "C" void kernel_launch(void* const* d_in, const int* in_sizes, int n_in,
                              void* d_out, int out_size, void* d_ws, size_t ws_size,
                              hipStream_t stream) {
    const float* means = (const float*)d_in[0];
    const float* meas = (const float*)d_in[3];
    const int* mask32 = (const int*)d_in[4];
    const unsigned char* mask8 = (const unsigned char*)d_in[4];
    const float* Rin = (const float*)d_in[5];

    int N = in_sizes[0] / NDIM;
    int M = in_sizes[3] / MDIM;

    float* out = (float*)d_out;
    float* pts = out;                               // [M,N,6]
    float* logw = out + (size_t)M * N * 6;          // [M,N]
    float* covs = out + (size_t)M * N * 7;          // [M,N,6,6]

    double* partials = (double*)d_ws;               // 27*NB_STATS f64 (27 KB)
    double* P64 = partials + 27 * NB_STATS;         // 36 f64

    int UBx = (N + 255) / 256;
    int MG = (M + GROUP_M - 1) / GROUP_M;
    int NC = (N + CHUNK - 1) / CHUNK;
    int CB = NC * MSPLIT;        // covs-role tasks
    int UB = UBx * MG;           // update-role tasks
    int TB = CB + UB;

    stats_partial_kernel<<<NB_STATS, 256, 0, stream>>>(means, N, partials);
    computeP_kernel<<<1, 256, 0, stream>>>(partials, N, P64);
    fused_all_kernel<<<TB, 256, 0, stream>>>(means, meas, mask32, mask8, Rin,
                                             P64, pts, logw, covs, N, M, CB, TB, UBx);
}

// Round 11
// 64.025 us; speedup vs baseline: 2.8536x; 1.0177x over previous
//
#include <hip/hip_runtime.h>
#include <math.h>

// EnGMPHD update kernel for MI355X (round 11).
// 2-launch pipeline:
//   1. stats_partial_kernel: 32 blocks, per-block partial sums (stat-major,
//      partials[stat*32 + blk])
//   2. fused_all_kernel (Bresenham-striped roles):
//      - per-block: 27 threads reduce 32 partials each -> stats; 36 threads
//        build P = bw6[|i-j|] * emp(i,j)   (bw6 computed on HOST: depends
//        only on N) -> sP (f64) / sPf (f32) in LDS
//      - covs role (c,g): 128 particles -> H/S/Chol/Sinv/K -> covs_post ->
//        LDS [128][36] (18 KB, 8 blocks/CU) -> slices m = g::8
//      - update role (mg,nb): per-thread particle pack in registers, then
//        GROUP_M=8 m's of pts (LDS repack -> contiguous float4) + logw

#define NDIM 6
#define MDIM 3
#define NB_STATS 32
#define MSPLIT 8   // covs role: each block writes M/MSPLIT = 4 slices
#define GROUP_M 8  // update role: m's per block
#define CHUNK 128  // covs role particles per block (18 KB LDS tile)
typedef float f32x4 __attribute__((ext_vector_type(4)));

struct BW6 {
    double w[6];  // bandwidth * exp(-d^2/18), d = |i-j|
};

__device__ __forceinline__ bool mask_true(const int* m32, const unsigned char* m8, int m) {
    return (m32[m] != 0) || (m8[m] != 0);
}

__global__ __launch_bounds__(256) void stats_partial_kernel(const float* __restrict__ means,
                                                            int N, double* __restrict__ partials) {
    double sx[6];
    double sxx[21];
#pragma unroll
    for (int i = 0; i < 6; ++i) sx[i] = 0.0;
#pragma unroll
    for (int i = 0; i < 21; ++i) sxx[i] = 0.0;

    int stride = NB_STATS * 256;
    for (int n = blockIdx.x * 256 + threadIdx.x; n < N; n += stride) {
        const float2* mp = (const float2*)(means + (size_t)n * 6);
        float2 a = mp[0], b = mp[1], c = mp[2];
        double x[6] = {a.x, a.y, b.x, b.y, c.x, c.y};
        int p = 0;
#pragma unroll
        for (int i = 0; i < 6; ++i) {
            sx[i] += x[i];
#pragma unroll
            for (int j = i; j < 6; ++j) sxx[p++] += x[i] * x[j];
        }
    }
#pragma unroll
    for (int off = 32; off >= 1; off >>= 1) {
#pragma unroll
        for (int i = 0; i < 6; ++i) sx[i] += __shfl_down(sx[i], off);
#pragma unroll
        for (int i = 0; i < 21; ++i) sxx[i] += __shfl_down(sxx[i], off);
    }
    __shared__ double lds[4][27];
    int wave = threadIdx.x >> 6;
    if ((threadIdx.x & 63) == 0) {
#pragma unroll
        for (int i = 0; i < 6; ++i) lds[wave][i] = sx[i];
#pragma unroll
        for (int i = 0; i < 21; ++i) lds[wave][6 + i] = sxx[i];
    }
    __syncthreads();
    if (threadIdx.x < 27) {
        double v = lds[0][threadIdx.x] + lds[1][threadIdx.x] +
                   lds[2][threadIdx.x] + lds[3][threadIdx.x];
        partials[threadIdx.x * NB_STATS + blockIdx.x] = v;
    }
}

struct PData {
    float hx0, hx1, hx2, logdet;
    float L00, L10, L11, L20, L21, L22;
    float Kf[6][3];
    float H[3][3];
};

// Per-particle measurement-model pipeline: f32 transcendentals, f64 algebra.
__device__ __forceinline__ void particle_compute(const float* __restrict__ means,
                                                 const float* __restrict__ Rin,
                                                 const double* __restrict__ sP,
                                                 int n, float* __restrict__ x, PData& o) {
    const float2* mp = (const float2*)(means + (size_t)n * 6);
    float2 ma = mp[0], mb = mp[1], mc = mp[2];
    x[0] = ma.x; x[1] = ma.y; x[2] = mb.x; x[3] = mb.y; x[4] = mc.x; x[5] = mc.y;
    float px = ma.x, py = ma.y, pz = mb.x;
    float s2 = px * px + py * py;
    float r2 = s2 + pz * pz;
    float rho = sqrtf(r2);
    float s = sqrtf(s2);
    o.hx0 = rho;
    o.hx1 = atan2f(py, px);
    o.hx2 = asinf(pz / rho);
    o.H[0][0] = px / rho; o.H[0][1] = py / rho; o.H[0][2] = pz / rho;
    o.H[1][0] = -py / s2; o.H[1][1] = px / s2;  o.H[1][2] = 0.0f;
    float invr2s = 1.0f / (r2 * s);
    o.H[2][0] = -pz * px * invr2s; o.H[2][1] = -pz * py * invr2s; o.H[2][2] = s / r2;

    double T[3][3];
#pragma unroll
    for (int i = 0; i < 3; ++i)
#pragma unroll
        for (int k = 0; k < 3; ++k)
            T[i][k] = (double)o.H[i][0] * sP[0 * 6 + k] + (double)o.H[i][1] * sP[1 * 6 + k] +
                      (double)o.H[i][2] * sP[2 * 6 + k];
    double S[3][3];
#pragma unroll
    for (int i = 0; i < 3; ++i)
#pragma unroll
        for (int l = 0; l < 3; ++l)
            S[i][l] = T[i][0] * (double)o.H[l][0] + T[i][1] * (double)o.H[l][1] +
                      T[i][2] * (double)o.H[l][2] + (double)Rin[i * 3 + l];

    double L00 = sqrt(S[0][0]);
    double L10 = S[1][0] / L00;
    double L20 = S[2][0] / L00;
    double L11 = sqrt(S[1][1] - L10 * L10);
    double L21 = (S[2][1] - L20 * L10) / L11;
    double L22 = sqrt(S[2][2] - L20 * L20 - L21 * L21);
    o.L00 = (float)L00; o.L10 = (float)L10; o.L11 = (float)L11;
    o.L20 = (float)L20; o.L21 = (float)L21; o.L22 = (float)L22;
    o.logdet = logf((float)(L00 * L11 * L22));

    double a00 = S[0][0], a01 = S[0][1], a02 = S[0][2];
    double a11 = S[1][1], a12 = S[1][2], a22 = S[2][2];
    double c00 = a11 * a22 - a12 * a12;
    double c01 = a02 * a12 - a01 * a22;
    double c02 = a01 * a12 - a02 * a11;
    double c11 = a00 * a22 - a02 * a02;
    double c12 = a01 * a02 - a00 * a12;
    double c22 = a00 * a11 - a01 * a01;
    double invdet = 1.0 / (a00 * c00 + a01 * c01 + a02 * c02);
    double Si[3][3] = {{c00 * invdet, c01 * invdet, c02 * invdet},
                       {c01 * invdet, c11 * invdet, c12 * invdet},
                       {c02 * invdet, c12 * invdet, c22 * invdet}};

#pragma unroll
    for (int i = 0; i < 6; ++i) {
        double pht[3];
#pragma unroll
        for (int k = 0; k < 3; ++k)
            pht[k] = sP[i * 6 + 0] * (double)o.H[k][0] + sP[i * 6 + 1] * (double)o.H[k][1] +
                     sP[i * 6 + 2] * (double)o.H[k][2];
#pragma unroll
        for (int l = 0; l < 3; ++l)
            o.Kf[i][l] = (float)(pht[0] * Si[0][l] + pht[1] * Si[1][l] + pht[2] * Si[2][l]);
    }
}

// Roles striped via Bresenham over TB = CB + UB tasks.
__global__ __launch_bounds__(256) void fused_all_kernel(const float* __restrict__ means,
                                                        const float* __restrict__ meas,
                                                        const int* __restrict__ mask32,
                                                        const unsigned char* __restrict__ mask8,
                                                        const float* __restrict__ Rin,
                                                        const double* __restrict__ partials,
                                                        BW6 bw,
                                                        float* __restrict__ pts,
                                                        float* __restrict__ logw,
                                                        float* __restrict__ covs,
                                                        int N, int M, int CB, int TB,
                                                        int UBx) {
    __shared__ double sStats[27];
    __shared__ double sP[36];
    __shared__ float sPf[36];
    __shared__ float sbuf[CHUNK * 36];  // 18 KB; update role uses first 6 KB

    int tid = threadIdx.x;
    if (tid < 27) {
        const double* src = partials + (size_t)tid * NB_STATS;
        double acc = 0.0;
#pragma unroll
        for (int k = 0; k < NB_STATS; ++k) acc += src[k];
        sStats[tid] = acc;
    }
    __syncthreads();
    if (tid < 36) {
        int ii = tid / 6, jj = tid - (tid / 6) * 6;
        int a = ii < jj ? ii : jj;
        int bb = ii < jj ? jj : ii;
        int p = a * 6 - (a * (a - 1)) / 2 + (bb - a);  // upper-tri index
        double mi = sStats[ii] / (double)N;
        double mj = sStats[jj] / (double)N;
        double emp = (sStats[6 + p] - (double)N * mi * mj) / (double)(N - 1);
        double v = bw.w[bb - a] * emp;
        sP[tid] = v;
        sPf[tid] = (float)v;
    }
    __syncthreads();

    long long b = blockIdx.x;
    int cbef = (int)(b * CB / TB);
    int cnext = (int)((b + 1) * CB / TB);

    if (cnext > cbef) {
        // ---------------- covs role (task cbef) ----------------
        int c = cbef / MSPLIT;
        int g = cbef - c * MSPLIT;
        int n0 = c * CHUNK;
        int count = N - n0;
        if (count > CHUNK) count = CHUNK;

        if (tid < count) {
            float x[6];
            PData o;
            particle_compute(means, Rin, sP, n0 + tid, x, o);
            float KH[6][3];
#pragma unroll
            for (int i = 0; i < 6; ++i)
#pragma unroll
                for (int j = 0; j < 3; ++j)
                    KH[i][j] = o.Kf[i][0] * o.H[0][j] + o.Kf[i][1] * o.H[1][j] +
                               o.Kf[i][2] * o.H[2][j];
            float* row = sbuf + tid * 36;
#pragma unroll
            for (int i = 0; i < 6; ++i)
#pragma unroll
                for (int j = 0; j < 6; ++j)
                    row[i * 6 + j] = sPf[i * 6 + j] - (KH[i][0] * sPf[0 * 6 + j] +
                                                       KH[i][1] * sPf[1 * 6 + j] +
                                                       KH[i][2] * sPf[2 * 6 + j]);
        }
        __syncthreads();

        int nf4 = count * 9;  // float4s in this tile
        const f32x4* s4 = (const f32x4*)sbuf;
        f32x4 z = {0.f, 0.f, 0.f, 0.f};
        for (int m = g; m < M; m += MSPLIT) {
            bool mk = mask_true(mask32, mask8, m);
            f32x4* d4 = (f32x4*)covs + ((size_t)m * N + n0) * 9;
            if (mk) {
                for (int i = tid; i < nf4; i += 256) d4[i] = s4[i];
            } else {
                for (int i = tid; i < nf4; i += 256) d4[i] = z;
            }
        }
        return;
    }

    // ---------------- update role (task b - cbef) ----------------
    int u = (int)(b - cbef);
    int mg = u / UBx;
    int nb = u - mg * UBx;
    int n0 = nb * 256;
    int count = N - n0;
    if (count > 256) count = 256;

    float x[6];
    PData o;
    if (tid < count) particle_compute(means, Rin, sP, n0 + tid, x, o);

#pragma unroll
    for (int j = 0; j < GROUP_M; ++j) {
        int m = mg * GROUP_M + j;
        if (m >= M) break;  // uniform across block
        bool mk = mask_true(mask32, mask8, m);
        __syncthreads();  // sbuf reuse guard
        if (tid < count) {
            float pt[6];
            if (mk) {
                float z0 = meas[m * 3 + 0];
                float z1 = meas[m * 3 + 1];
                float z2v = meas[m * 3 + 2];
                float i0 = o.hx0 - z0, i1 = o.hx1 - z1, i2 = o.hx2 - z2v;
#pragma unroll
                for (int d = 0; d < 6; ++d)
                    pt[d] = x[d] - (o.Kf[d][0] * i0 + o.Kf[d][1] * i1 + o.Kf[d][2] * i2);
                float px = pt[0], py = pt[1], pz = pt[2];
                float r2 = px * px + py * py + pz * pz;
                float rho = sqrtf(r2);
                float d0 = z0 - rho;
                float d1 = z1 - atan2f(py, px);
                float d2 = z2v - asinf(pz / rho);
                float y0 = d0 / o.L00;
                float y1 = (d1 - o.L10 * y0) / o.L11;
                float y2 = (d2 - o.L20 * y0 - o.L21 * y1) / o.L22;
                float quad = y0 * y0 + y1 * y1 + y2 * y2;
                logw[(size_t)m * N + n0 + tid] = -0.5f * quad - o.logdet - 2.7568156f;
            } else {
#pragma unroll
                for (int d = 0; d < 6; ++d) pt[d] = 0.f;
                logw[(size_t)m * N + n0 + tid] = -INFINITY;
            }
#pragma unroll
            for (int d = 0; d < 6; ++d) sbuf[tid * 6 + d] = pt[d];
        }
        __syncthreads();
        int nf = count * 6;
        float* dst = pts + ((size_t)m * N + n0) * 6;
        const f32x4* s4 = (const f32x4*)sbuf;
        f32x4* d4 = (f32x4*)dst;
        int n4 = nf >> 2;
        for (int i = tid; i < n4; i += 256) d4[i] = s4[i];
        for (int i = (n4 << 2) + tid; i < nf; i += 256) dst[i] = sbuf[i];
    }
}

extern "C" void kernel_launch(void* const* d_in, const int* in_sizes, int n_in,
                              void* d_out, int out_size, void* d_ws, size_t ws_size,
                              hipStream_t stream) {
    const float* means = (const float*)d_in[0];
    const float* meas = (const float*)d_in[3];
    const int* mask32 = (const int*)d_in[4];
    const unsigned char* mask8 = (const unsigned char*)d_in[4];
    const float* Rin = (const float*)d_in[5];

    int N = in_sizes[0] / NDIM;
    int M = in_sizes[3] / MDIM;

    float* out = (float*)d_out;
    float* pts = out;                               // [M,N,6]
    float* logw = out + (size_t)M * N * 6;          // [M,N]
    float* covs = out + (size_t)M * N * 7;          // [M,N,6,6]

    double* partials = (double*)d_ws;               // 27*NB_STATS f64 (6.9 KB)

    // Host-side: bandwidth * localization weights (depend only on N, d).
    BW6 bw;
    double bandwidth = pow(4.0 / ((double)N * 8.0), 0.2);  // (4/(n(d+2)))^(2/(d+4)), d=6
    for (int d = 0; d < 6; ++d)
        bw.w[d] = bandwidth * exp(-(double)(d * d) / 18.0);  // L = 3.0

    int UBx = (N + 255) / 256;
    int MG = (M + GROUP_M - 1) / GROUP_M;
    int NC = (N + CHUNK - 1) / CHUNK;
    int CB = NC * MSPLIT;        // covs-role tasks
    int UB = UBx * MG;           // update-role tasks
    int TB = CB + UB;

    stats_partial_kernel<<<NB_STATS, 256, 0, stream>>>(means, N, partials);
    fused_all_kernel<<<TB, 256, 0, stream>>>(means, meas, mask32, mask8, Rin,
                                             partials, bw, pts, logw, covs,
                                             N, M, CB, TB, UBx);
}